// Round 9
// baseline (1502.652 us; speedup 1.0000x reference)
//
#include <hip/hip_runtime.h>
#include <hip/hip_bf16.h>
#include <math.h>

#define BB 512
#define SS 512
#define MM 64
#define DK 128
#define DV 256
#define DF 128
#define CHUNK 16
#define NCHUNK (SS/CHUNK)

typedef __attribute__((ext_vector_type(8))) short s8v;            // 8 bf16
typedef __attribute__((ext_vector_type(4))) float f4v;            // MFMA acc
typedef __attribute__((ext_vector_type(8))) unsigned short u16x8; // 16B of bf16

#define MFMA16(a,b,c) __builtin_amdgcn_mfma_f32_16x16x32_bf16((a),(b),(c),0,0,0)

// ---- workspace layout ----
// ws[0..15] floats: loss accumulators (fallback paths). u16 pack region at byte 64:
#define EAP_OFF 0         // erase|add packed B-frags, N=512, K=256 (131072 u16)
#define KTP_OFF 131072    // key   packed, N=64,  K=128 (8192)
#define ITP_OFF 139264    // input packed, N=128, K=128 (16384)
#define RTP_OFF 155648    // read  packed, N=128, K=384 (49152) -> end 204800
// byte offsets from ws base:
#define WTAB_BYTE 409664                      // f32 [10001][64]   softmax'd w
#define IET_BYTE  2969920                     // bf16 [10001][128]: iet (fallback) OR riW2=ie@W2+read_b (fast path)
#define EAT_BYTE  5530176                     // bf16 [20001][512] sig(er)|tanh(ad)
#define WS_NEED2  26011200ull
#define READS_BYTE 26011264ull                // bf16 [512][512][256] read vectors
#define WS_NEED3  (READS_BYTE + (size_t)BB*SS*DV*2)
// loss partials: 2 f32 at the head of each rce block's (dead-after-stage) reads slice
#define PART_STRIDE_B 32768                   // 64 rows * 256 * 2B

__device__ __forceinline__ unsigned short f2bf(float x) {
    union { float f; unsigned u; } v; v.f = x;
    unsigned r = v.u + 0x7fffu + ((v.u >> 16) & 1u);
    return (unsigned short)(r >> 16);
}
__device__ __forceinline__ float bf2f(unsigned short h) {
    union { unsigned u; float f; } v; v.u = ((unsigned)h) << 16;
    return v.f;
}
__device__ __forceinline__ float u2f(unsigned u) {
    union { unsigned x; float f; } v; v.x = u; return v.f;
}
__device__ __forceinline__ float sigmoidf_(float x) { return 1.0f / (1.0f + __expf(-x)); }
__device__ __forceinline__ float fast_tanh(float x) {
    float e = __expf(2.0f * x);
    return 1.0f - 2.0f / (e + 1.0f);
}

// ======================= prep: pack weights =======================
__global__ void prep_kernel(const float* __restrict__ ew, const float* __restrict__ aw,
                            const float* __restrict__ km, const float* __restrict__ iw,
                            const float* __restrict__ rw, float* __restrict__ wsf) {
    int tid = blockIdx.x * 256 + threadIdx.x;
    int stride = gridDim.x * 256;
    if (tid < 2) wsf[tid] = 0.0f;
    unsigned short* bp = (unsigned short*)(wsf + 16);

    for (int i = tid; i < 131072; i += stride) {           // EAP: nf<32, ks<8
        int e = i & 7, l = (i >> 3) & 63, ks = (i >> 9) & 7, nf = i >> 12;
        int k = ks*32 + (l >> 4)*8 + e;
        int n = nf*16 + (l & 15);
        float v = (n < 256) ? ew[n*DV + k] : aw[(n-256)*DV + k];
        bp[EAP_OFF + i] = f2bf(v);
    }
    for (int i = tid; i < 8192; i += stride) {             // KTP
        int e = i & 7, l = (i >> 3) & 63, ks = (i >> 9) & 3, nf = i >> 11;
        int k = ks*32 + (l >> 4)*8 + e;
        int m = nf*16 + (l & 15);
        bp[KTP_OFF + i] = f2bf(km[m*DK + k]);
    }
    for (int i = tid; i < 16384; i += stride) {            // ITP
        int e = i & 7, l = (i >> 3) & 63, ks = (i >> 9) & 3, nf = i >> 11;
        int k = ks*32 + (l >> 4)*8 + e;
        int f = nf*16 + (l & 15);
        bp[ITP_OFF + i] = f2bf(iw[f*DK + k]);
    }
    for (int i = tid; i < 49152; i += stride) {            // RTP: nf<8, ks<12
        int e = i & 7, l = (i >> 3) & 63, g = i >> 9;
        int ks = g % 12, nf = g / 12;
        int j = ks*32 + (l >> 4)*8 + e;
        int f = nf*16 + (l & 15);
        bp[RTP_OFF + i] = f2bf(rw[f*(DV+DF) + j]);
    }
}

// ======================= table kernel =======================
// blocks [0,157): q-tables (wtab + {iet | riW2}); blocks [157,470): qa-tables (ea)
__launch_bounds__(256, 2)
__global__ void table_kernel(const float* __restrict__ q_embed, const float* __restrict__ qa_embed,
                             const float* __restrict__ erase_b, const float* __restrict__ add_b,
                             const float* __restrict__ input_b, const float* __restrict__ read_b,
                             int rw2flag, float* __restrict__ ws) {
    __shared__ __align__(128) char tsm[65536];
    const int tid  = threadIdx.x;
    const int lane = tid & 63;
    const int wave = tid >> 6;       // 0..3
    const int arow = lane & 15;
    const int ag   = lane >> 4;

    const unsigned short* wsb = (const unsigned short*)(ws + 16);
    const s8v* eap = (const s8v*)(wsb + EAP_OFF);
    const s8v* ktp = (const s8v*)(wsb + KTP_OFF);
    const s8v* itp = (const s8v*)(wsb + ITP_OFF);
    const s8v* rtp = (const s8v*)(wsb + RTP_OFF);
    float*          wtab = (float*)((char*)ws + WTAB_BYTE);
    unsigned short* iet  = (unsigned short*)((char*)ws + IET_BYTE);   // iet OR riW2 slot
    unsigned short* eat  = (unsigned short*)((char*)ws + EAT_BYTE);

    if (blockIdx.x < 157) {
        const int r0 = blockIdx.x * 64;
        char*  q16   = tsm;                    // [64][256B] bf16 swizzled
        float* sc    = (float*)(tsm + 16384);  // [64][68] f32
        unsigned short* iest = (unsigned short*)(tsm + 33792); // [64][128] linear

        #pragma unroll
        for (int it = 0; it < 8; ++it) {
            int u = it*256 + tid;
            int row = u >> 5, c4 = u & 31;
            int sr = r0 + row; if (sr > 10000) sr = 10000;
            float4 v = *(const float4*)(q_embed + sr*DK + c4*4);
            ushort4 p; p.x = f2bf(v.x); p.y = f2bf(v.y); p.z = f2bf(v.z); p.w = f2bf(v.w);
            *(ushort4*)(q16 + ((row*256 + c4*8) ^ ((row & 7) << 4))) = p;
        }
        __syncthreads();

        {
            s8v a[4];
            #pragma unroll
            for (int ks = 0; ks < 4; ++ks)
                a[ks] = *(const s8v*)(q16 + (((wave*16+arow)*256 + ks*64 + ag*16) ^ ((arow & 7) << 4)));
            #pragma unroll
            for (int j = 0; j < 4; ++j) {
                f4v cc = {0.f,0.f,0.f,0.f};
                #pragma unroll
                for (int ks = 0; ks < 4; ++ks) cc = MFMA16(a[ks], ktp[(j*4 + ks)*64 + lane], cc);
                #pragma unroll
                for (int r = 0; r < 4; ++r)
                    sc[(wave*16 + ag*4 + r)*68 + j*16 + arow] = cc[r];
            }
            __syncthreads();

            #pragma unroll
            for (int k = 0; k < 16; ++k) {
                int rr = wave*16 + k;
                float v = sc[rr*68 + lane];
                float mx = v;
                #pragma unroll
                for (int off = 32; off; off >>= 1) mx = fmaxf(mx, __shfl_xor(mx, off));
                float e = __expf(v - mx);
                float sum = e;
                #pragma unroll
                for (int off = 32; off; off >>= 1) sum += __shfl_xor(sum, off);
                if (r0 + rr < 10001) wtab[(r0 + rr)*64 + lane] = e / sum;
            }

            #pragma unroll
            for (int j = 0; j < 8; ++j) {                  // ie = tanh(q@Wi + ib) -> iest linear
                f4v cc = {0.f,0.f,0.f,0.f};
                #pragma unroll
                for (int ks = 0; ks < 4; ++ks) cc = MFMA16(a[ks], itp[(j*4 + ks)*64 + lane], cc);
                float bias = input_b[j*16 + arow];
                #pragma unroll
                for (int r = 0; r < 4; ++r)
                    iest[(wave*16 + ag*4 + r)*128 + j*16 + arow] = f2bf(fast_tanh(cc[r] + bias));
            }
        }
        __syncthreads();

        if (rw2flag) {
            // riW2 = iest @ W2 + read_b  (W2 = rtp ks 8..11), overwrite iest in place.
            s8v af2[4];
            #pragma unroll
            for (int ks2 = 0; ks2 < 4; ++ks2)
                af2[ks2] = *(const s8v*)((const char*)iest + (wave*16+arow)*256 + ks2*64 + ag*16);
            f4v acc2[8];
            #pragma unroll
            for (int j = 0; j < 8; ++j) acc2[j] = (f4v){0.f,0.f,0.f,0.f};
            #pragma unroll
            for (int ks2 = 0; ks2 < 4; ++ks2)
                #pragma unroll
                for (int j = 0; j < 8; ++j)
                    acc2[j] = MFMA16(af2[ks2], rtp[(j*12 + 8 + ks2)*64 + lane], acc2[j]);
            #pragma unroll
            for (int j = 0; j < 8; ++j) {
                float rb = read_b[j*16 + arow];
                #pragma unroll
                for (int r = 0; r < 4; ++r)
                    iest[(wave*16 + ag*4 + r)*128 + j*16 + arow] = f2bf(acc2[j][r] + rb);
            }
            __syncthreads();
        }
        #pragma unroll
        for (int it = 0; it < 4; ++it) {                   // coalesced store (iet or riW2)
            int u = it*256 + tid;
            int row = u >> 4, c8 = u & 15;
            if (r0 + row < 10001)
                *(u16x8*)(iet + (r0 + row)*128 + c8*8) = *(const u16x8*)(iest + row*128 + c8*8);
        }
    } else {
        const int r0 = (blockIdx.x - 157) * 64;
        char* qa16 = tsm;                                    // [64][512B] swizzled (32KB)
        unsigned short* east = (unsigned short*)(tsm + 32768); // [64][256] half-tile (32KB)

        #pragma unroll
        for (int it = 0; it < 16; ++it) {
            int u = it*256 + tid;
            int row = u >> 6, c4 = u & 63;
            int sr = r0 + row; if (sr > 20000) sr = 20000;
            float4 v = *(const float4*)(qa_embed + sr*DV + c4*4);
            ushort4 p; p.x = f2bf(v.x); p.y = f2bf(v.y); p.z = f2bf(v.z); p.w = f2bf(v.w);
            *(ushort4*)(qa16 + ((row*512 + c4*8) ^ ((row & 7) << 4))) = p;
        }
        __syncthreads();

        s8v af[8];
        #pragma unroll
        for (int ks = 0; ks < 8; ++ks)
            af[ks] = *(const s8v*)(qa16 + (((wave*16+arow)*512 + ks*64 + ag*16) ^ ((arow & 7) << 4)));

        for (int h = 0; h < 2; ++h) {                        // two n-halves of 256
            #pragma unroll
            for (int i = 0; i < 16; ++i) {
                int nt = h*16 + i;
                f4v cc = {0.f,0.f,0.f,0.f};
                #pragma unroll
                for (int ks = 0; ks < 8; ++ks) cc = MFMA16(af[ks], eap[(nt*8 + ks)*64 + lane], cc);
                int n = nt*16 + arow;
                float bias = (n < 256) ? erase_b[n] : add_b[n - 256];
                #pragma unroll
                for (int r = 0; r < 4; ++r) {
                    float v = cc[r] + bias;
                    float res = (n < 256) ? sigmoidf_(v) : fast_tanh(v);
                    east[(wave*16 + ag*4 + r)*256 + (n - h*256)] = f2bf(res);
                }
            }
            __syncthreads();
            #pragma unroll
            for (int it = 0; it < 8; ++it) {
                int u = it*256 + tid;
                int row = u >> 5, c8 = u & 31;
                if (r0 + row < 20001)
                    *(u16x8*)(eat + (size_t)(r0 + row)*512 + h*256 + c8*8) =
                        *(const u16x8*)(east + row*256 + c8*8);
            }
            __syncthreads();
        }
    }
}

// ======================= scan2: d-split recurrence, full residency =======================
// grid 2048 = 8 blocks/CU exactly; VGPR<=64, LDS 17.4KB -> 8 blocks/CU resident.
__launch_bounds__(256, 8)
__global__ void scan2_kernel(const int* __restrict__ q_data, const int* __restrict__ qa_data,
                             const float* __restrict__ init_mv,
                             float* __restrict__ ws) {
    __shared__ float          wf [CHUNK][68];     // softmax w rows (wave-uniform reads)
    __shared__ unsigned       eaL[CHUNK][68];     // interleaved e(lo)|a(hi) bf16 pairs per d
    __shared__ unsigned short rdp[CHUNK][4][68];  // bf16 read partials per m-quarter

    const int bid = blockIdx.x;
    const int xcd = bid & 7, idx = bid >> 3;
    const int b   = xcd*64 + (idx >> 2);
    const int dq  = idx & 3;
    const int tid = threadIdx.x;
    const int d   = tid & 63;
    const int mq  = tid >> 6;

    const float*          wtab  = (const float*)((const char*)ws + WTAB_BYTE);
    const unsigned short* eat   = (const unsigned short*)((const char*)ws + EAT_BYTE);
    unsigned short*       reads = (unsigned short*)((char*)ws + READS_BYTE);

    float mv[16];
    #pragma unroll
    for (int j = 0; j < 16; ++j) mv[j] = init_mv[(mq*16 + j)*DV + dq*64 + d];

    const int base = b * SS;
    const bool eaRole = (tid < 128);
    const int erow = tid >> 3;
    const int eu   = tid & 7;
    const int wrow = (tid - 128) >> 3;
    const int wu   = tid & 7;

    int ia0, iq0, ia1, iq1;
    u16x8 per, pad_; float4 pw0, pw1;

    auto loadidx = [&](int cc, int& xa, int& xq) {
        if (eaRole) xa = qa_data[base + cc*CHUNK + erow];
        else        xq = q_data [base + cc*CHUNK + wrow];
    };
    auto loadrows = [&]() {
        if (eaRole) {
            per  = *(const u16x8*)(eat + (size_t)ia0*512 +       dq*64 + eu*8);
            pad_ = *(const u16x8*)(eat + (size_t)ia0*512 + 256 + dq*64 + eu*8);
        } else {
            pw0 = *(const float4*)(wtab + iq0*64 + wu*8);
            pw1 = *(const float4*)(wtab + iq0*64 + wu*8 + 4);
        }
    };
    auto storerows = [&]() {
        if (eaRole) {
            unsigned pk[8];
            #pragma unroll
            for (int i = 0; i < 8; ++i)
                pk[i] = (unsigned)per[i] | ((unsigned)pad_[i] << 16);
            *(uint4*)&eaL[erow][eu*8]     = *(uint4*)&pk[0];
            *(uint4*)&eaL[erow][eu*8 + 4] = *(uint4*)&pk[4];
        } else {
            *(float4*)&wf[wrow][wu*8]     = pw0;
            *(float4*)&wf[wrow][wu*8 + 4] = pw1;
        }
    };

    loadidx(0, ia0, iq0);
    loadrows();
    loadidx(1, ia1, iq1);

    for (int c = 0; c < NCHUNK; ++c) {
        storerows();
        __syncthreads();                               // B1: staged
        ia0 = ia1; iq0 = iq1;
        if (c + 1 < NCHUNK) loadrows();
        { int c2 = (c + 2 < NCHUNK) ? c + 2 : NCHUNK - 1; loadidx(c2, ia1, iq1); }

        float4 wc0, wc1, wc2, wc3; unsigned eac;
        {
            const float4* wr = (const float4*)&wf[0][mq*16];
            wc0 = wr[0]; wc1 = wr[1]; wc2 = wr[2]; wc3 = wr[3];
            eac = eaL[0][d];
        }
        #pragma unroll
        for (int s = 0; s < CHUNK; ++s) {
            int sn = (s + 1 < CHUNK) ? s + 1 : s;
            const float4* wr = (const float4*)&wf[sn][mq*16];
            float4 wn0 = wr[0], wn1 = wr[1], wn2 = wr[2], wn3 = wr[3];
            unsigned ean = eaL[sn][d];

            float e = u2f(eac << 16);
            float a = u2f(eac & 0xffff0000u);
            float r0 = 0.f, r1 = 0.f, r2 = 0.f, r3 = 0.f;
            #define STEP(W, J) \
                r0 = fmaf(W.x, mv[J+0], r0); mv[J+0] = fmaf(W.x, fmaf(-mv[J+0], e, a), mv[J+0]); \
                r1 = fmaf(W.y, mv[J+1], r1); mv[J+1] = fmaf(W.y, fmaf(-mv[J+1], e, a), mv[J+1]); \
                r2 = fmaf(W.z, mv[J+2], r2); mv[J+2] = fmaf(W.z, fmaf(-mv[J+2], e, a), mv[J+2]); \
                r3 = fmaf(W.w, mv[J+3], r3); mv[J+3] = fmaf(W.w, fmaf(-mv[J+3], e, a), mv[J+3]);
            STEP(wc0, 0) STEP(wc1, 4) STEP(wc2, 8) STEP(wc3, 12)
            #undef STEP
            rdp[s][mq][d] = f2bf((r0 + r1) + (r2 + r3));

            wc0 = wn0; wc1 = wn1; wc2 = wn2; wc3 = wn3; eac = ean;
        }
        __syncthreads();                               // B2: partials in LDS

        {
            int s = tid >> 4, d0 = (tid & 15) * 4;
            float a0 = 0.f, a1 = 0.f, a2 = 0.f, a3 = 0.f;
            #pragma unroll
            for (int m2 = 0; m2 < 4; ++m2) {
                ushort4 v = *(const ushort4*)&rdp[s][m2][d0];
                a0 += bf2f(v.x); a1 += bf2f(v.y); a2 += bf2f(v.z); a3 += bf2f(v.w);
            }
            ushort4 o; o.x = f2bf(a0); o.y = f2bf(a1); o.z = f2bf(a2); o.w = f2bf(a3);
            *(ushort4*)(reads + (size_t)(base + c*CHUNK + s)*DV + dq*64 + d0) = o;
        }
    }
}

// ======================= rce kernel: [64][256]x[256][128] MFMA + riW2 + pred (atomic-free) =======================
__launch_bounds__(256, 2)
__global__ void rce_kernel(const int* __restrict__ q_data, const float* __restrict__ target,
                           const float* __restrict__ predict_w, const float* __restrict__ predict_b,
                           float* __restrict__ ws, float* __restrict__ out) {
    __shared__ __align__(128) char cat16[33792];        // [64][512B] swizzled; overlaid by rce_f [64][132] f32
    __shared__ __align__(16) unsigned short rw2s[64][128];
    __shared__ float lred[4][2];
    float* rce_f = (float*)cat16;

    const int blk  = blockIdx.x;
    const int b    = blk >> 3;
    const int s0   = (blk & 7) * 64;
    const int tid  = threadIdx.x;
    const int lane = tid & 63;
    const int wave = tid >> 6;
    const int arow = lane & 15;
    const int ag   = lane >> 4;

    const unsigned short* wsb   = (const unsigned short*)(ws + 16);
    const s8v*            rtp   = (const s8v*)(wsb + RTP_OFF);
    const unsigned short* rw2t  = (const unsigned short*)((const char*)ws + IET_BYTE);
    const unsigned short* reads = (const unsigned short*)((const char*)ws + READS_BYTE);

    #pragma unroll
    for (int it = 0; it < 8; ++it) {                 // stage reads -> cat (K=256)
        int u = it*256 + tid, row = u >> 5, cu = u & 31;
        u16x8 v = *(const u16x8*)(reads + (size_t)(b*SS + s0 + row)*DV + cu*8);
        *(u16x8*)(cat16 + ((row*512 + cu*16) ^ ((row & 7) << 4))) = v;
    }
    #pragma unroll
    for (int it = 0; it < 4; ++it) {                 // stage riW2 rows
        int u = it*256 + tid, row = u >> 4, cu = u & 15;
        int iq = q_data[b*SS + s0 + row];
        *(u16x8*)(&rw2s[row][cu*8]) = *(const u16x8*)(rw2t + (size_t)iq*128 + cu*8);
    }
    __syncthreads();

    f4v acc[8];
    #pragma unroll
    for (int n = 0; n < 8; ++n) acc[n] = (f4v){0.f,0.f,0.f,0.f};
    #pragma unroll
    for (int ks = 0; ks < 8; ++ks) {
        int row = wave*16 + arow;
        s8v a = *(const s8v*)(cat16 + ((row*512 + ks*64 + ag*16) ^ ((row & 7) << 4)));
        #pragma unroll
        for (int n = 0; n < 8; ++n)
            acc[n] = MFMA16(a, rtp[(n*12 + ks)*64 + lane], acc[n]);
    }
    __syncthreads();                                  // cat reads done before rce_f overlay

    #pragma unroll
    for (int n = 0; n < 8; ++n) {
        #pragma unroll
        for (int r = 0; r < 4; ++r) {
            int rr = wave*16 + ag*4 + r, col = n*16 + arow;
            rce_f[rr*132 + col] = fast_tanh(acc[n][r] + bf2f(rw2s[rr][col]));
        }
    }
    __syncthreads();

    const float pw_lo = predict_w[lane];
    const float pw_hi = predict_w[lane + 64];
    float local_loss = 0.f, local_cnt = 0.f;
    #pragma unroll
    for (int k = 0; k < 16; ++k) {
        int r = wave*16 + k;
        float p = fmaf(pw_lo, rce_f[r*132 + lane], pw_hi * rce_f[r*132 + 64 + lane]);
        #pragma unroll
        for (int off = 32; off; off >>= 1) p += __shfl_xor(p, off);
        if (lane == 0) {
            p += predict_b[0];
            int gi = b*SS + s0 + r;
            float t = target[gi];
            bool mask = t >= 0.0f;
            out[gi] = sigmoidf_(p);
            out[BB*SS + 1 + gi] = sigmoidf_(mask ? p : 0.0f);
            out[2*BB*SS + 1 + gi] = mask ? t : 0.0f;
            if (mask) {
                local_loss += fmaxf(p, 0.0f) - p*t + log1pf(__expf(-fabsf(p)));
                local_cnt  += 1.0f;
            }
        }
    }
    // atomic-free loss: block-reduce via LDS, store 1 pair into this block's dead reads slice
    if (lane == 0) { lred[wave][0] = local_loss; lred[wave][1] = local_cnt; }
    __syncthreads();
    if (tid == 0) {
        float L = lred[0][0] + lred[1][0] + lred[2][0] + lred[3][0];
        float C = lred[0][1] + lred[1][1] + lred[2][1] + lred[3][1];
        float* part = (float*)((char*)ws + READS_BYTE + (size_t)blk * PART_STRIDE_B);
        part[0] = L; part[1] = C;
    }
}

// ======================= finish: deterministic loss reduce =======================
__global__ void finish_kernel(float* __restrict__ ws, float* __restrict__ out, int mode) {
    if (mode == 0) {
        if (threadIdx.x == 0) out[BB*SS] = ws[0] / fmaxf(ws[1], 1.0f);
        return;
    }
    __shared__ float sl[4][2];
    const int tid = threadIdx.x, lane = tid & 63, wave = tid >> 6;
    const char* base = (const char*)ws + READS_BYTE;
    float L = 0.f, C = 0.f;
    for (int i = tid; i < 4096; i += 256) {
        const float* p = (const float*)(base + (size_t)i * PART_STRIDE_B);
        L += p[0]; C += p[1];
    }
    #pragma unroll
    for (int off = 32; off; off >>= 1) {
        L += __shfl_xor(L, off);
        C += __shfl_xor(C, off);
    }
    if (lane == 0) { sl[wave][0] = L; sl[wave][1] = C; }
    __syncthreads();
    if (tid == 0) {
        float LL = sl[0][0] + sl[1][0] + sl[2][0] + sl[3][0];
        float CC = sl[0][1] + sl[1][1] + sl[2][1] + sl[3][1];
        out[BB*SS] = LL / fmaxf(CC, 1.0f);
    }
}

// ======================= round-5 scan kernel (fallback, ws >= 26MB) =======================
__launch_bounds__(512, 2)
__global__ void scan_kernel(const int* __restrict__ q_data, const int* __restrict__ qa_data,
                            const float* __restrict__ target,
                            const float* __restrict__ init_mv,
                            const float* __restrict__ read_b,
                            const float* __restrict__ predict_w, const float* __restrict__ predict_b,
                            float* __restrict__ ws, float* __restrict__ out) {
    __shared__ __align__(128) char smem[50176];
    char*           cat16 = smem;
    float*          wf    = (float*)(smem + 12288);
    unsigned short* eaL   = (unsigned short*)(smem + 16640);
    unsigned short* rdp   = (unsigned short*)(smem + 33280);
    float*          rce_f = (float*)(smem + 41728);

    const int b    = blockIdx.x;
    const int tid  = threadIdx.x;
    const int lane = tid & 63;
    const int wave = tid >> 6;
    const int arow = lane & 15;
    const int ag   = lane >> 4;
    const int d    = tid & 255;
    const int half = tid >> 8;

    const unsigned short* wsb = (const unsigned short*)(ws + 16);
    const s8v* rtp = (const s8v*)(wsb + RTP_OFF);
    const float*          wtab = (const float*)((const char*)ws + WTAB_BYTE);
    const unsigned short* iet  = (const unsigned short*)((const char*)ws + IET_BYTE);
    const unsigned short* eat  = (const unsigned short*)((const char*)ws + EAT_BYTE);

    float mv[32];
    #pragma unroll
    for (int i = 0; i < 32; ++i) mv[i] = init_mv[(half*32 + i)*DV + d];

    const float rb    = read_b[wave*16 + arow];
    const float pw_lo = predict_w[lane];
    const float pw_hi = predict_w[lane + 64];

    const int base  = b * SS;
    const int erow  = tid >> 5;
    const int eunit = tid & 31;
    const int role  = tid >> 8;
    const int grow  = (tid >> 4) & 15;
    const int gunit = tid & 15;

    int iqa0, iq0, iqa1, iq1;
    u16x8 pe0, pe1, pie;
    float4 pwf;

    auto loadidx = [&](int cc, int& xa, int& xq) {
        xa = qa_data[base + cc*CHUNK + erow];
        xq = q_data [base + cc*CHUNK + grow];
    };
    auto loadrows = [&]() {
        const unsigned short* er_ptr = eat + (size_t)iqa0*512 + eunit*16;
        pe0 = *(const u16x8*)(er_ptr);
        pe1 = *(const u16x8*)(er_ptr + 8);
        if (role == 0) pwf = *(const float4*)(wtab + iq0*64 + gunit*4);
        else           pie = *(const u16x8*)(iet + (size_t)iq0*128 + gunit*8);
    };
    auto storerows = [&]() {
        *(u16x8*)(eaL + erow*520 + eunit*16)     = pe0;
        *(u16x8*)(eaL + erow*520 + eunit*16 + 8) = pe1;
        if (role == 0) *(float4*)((char*)wf + grow*272 + gunit*16) = pwf;
        else *(u16x8*)(cat16 + ((grow*768 + 512 + gunit*16) ^ ((grow & 7) << 4))) = pie;
    };

    loadidx(0, iqa0, iq0);
    loadrows();
    loadidx(1, iqa1, iq1);

    float local_loss = 0.0f, local_cnt = 0.0f;

    for (int c = 0; c < NCHUNK; ++c) {
        storerows();
        __syncthreads();
        iqa0 = iqa1; iq0 = iq1;
        if (c + 1 < NCHUNK) loadrows();
        { int c2 = (c + 2 < NCHUNK) ? c + 2 : NCHUNK - 1; loadidx(c2, iqa1, iq1); }

        for (int s = 0; s < CHUNK; ++s) {
            float e = bf2f(eaL[s*520 + d]);
            float a = bf2f(eaL[s*520 + 256 + d]);
            const float4* wr4 = (const float4*)(wf + s*68 + half*32);
            float r0 = 0.f, r1 = 0.f, r2 = 0.f, r3 = 0.f;
            #pragma unroll
            for (int j = 0; j < 8; ++j) {
                float4 w = wr4[j];
                r0 = fmaf(w.x, mv[j*4+0], r0); mv[j*4+0] = fmaf(w.x, fmaf(-mv[j*4+0], e, a), mv[j*4+0]);
                r1 = fmaf(w.y, mv[j*4+1], r1); mv[j*4+1] = fmaf(w.y, fmaf(-mv[j*4+1], e, a), mv[j*4+1]);
                r2 = fmaf(w.z, mv[j*4+2], r2); mv[j*4+2] = fmaf(w.z, fmaf(-mv[j*4+2], e, a), mv[j*4+2]);
                r3 = fmaf(w.w, mv[j*4+3], r3); mv[j*4+3] = fmaf(w.w, fmaf(-mv[j*4+3], e, a), mv[j*4+3]);
            }
            float rd = (r0 + r1) + (r2 + r3);
            if (half == 0) {
                *(unsigned short*)(cat16 + ((s*768 + d*2) ^ ((s & 7) << 4))) = f2bf(rd);
            } else {
                rdp[s*264 + d] = f2bf(rd);
            }
        }
        __syncthreads();

        if (half == 0) {
            #pragma unroll
            for (int s = 0; s < CHUNK; ++s) {
                unsigned short* p = (unsigned short*)(cat16 + ((s*768 + d*2) ^ ((s & 7) << 4)));
                *p = f2bf(bf2f(*p) + bf2f(rdp[s*264 + d]));
            }
        }
        __syncthreads();

        {
            f4v cc = {0.f,0.f,0.f,0.f};
            #pragma unroll
            for (int ks = 0; ks < 12; ++ks) {
                s8v a = *(const s8v*)(cat16 + ((arow*768 + ks*64 + ag*16) ^ ((arow & 7) << 4)));
                cc = MFMA16(a, rtp[(wave*12 + ks)*64 + lane], cc);
            }
            #pragma unroll
            for (int r = 0; r < 4; ++r)
                rce_f[(ag*4 + r)*132 + wave*16 + arow] = fast_tanh(cc[r] + rb);
        }
        __syncthreads();

        #pragma unroll
        for (int k = 0; k < 2; ++k) {
            int r = wave*2 + k;
            float p = fmaf(pw_lo, rce_f[r*132 + lane], pw_hi * rce_f[r*132 + 64 + lane]);
            #pragma unroll
            for (int off = 32; off; off >>= 1) p += __shfl_xor(p, off);
            if (lane == 0) {
                p += predict_b[0];
                int gi = b*SS + c*CHUNK + r;
                float t = target[gi];
                bool mask = t >= 0.0f;
                out[gi] = sigmoidf_(p);
                float pm = mask ? p : 0.0f;
                out[BB*SS + 1 + gi] = sigmoidf_(pm);
                out[2*BB*SS + 1 + gi] = mask ? t : 0.0f;
                if (mask) {
                    local_loss += fmaxf(p, 0.0f) - p*t + log1pf(__expf(-fabsf(p)));
                    local_cnt  += 1.0f;
                }
            }
        }
    }

    #pragma unroll
    for (int off = 32; off; off >>= 1) {
        local_loss += __shfl_xor(local_loss, off);
        local_cnt  += __shfl_xor(local_cnt, off);
    }
    if (lane == 0) {
        atomicAdd(&ws[0], local_loss);
        atomicAdd(&ws[1], local_cnt);
    }
}

extern "C" void kernel_launch(void* const* d_in, const int* in_sizes, int n_in,
                              void* d_out, int out_size, void* d_ws, size_t ws_size,
                              hipStream_t stream) {
    const int*   q_data    = (const int*)d_in[0];
    const int*   qa_data   = (const int*)d_in[1];
    const float* target    = (const float*)d_in[2];
    const float* q_embed   = (const float*)d_in[3];
    const float* qa_embed  = (const float*)d_in[4];
    const float* key_mem   = (const float*)d_in[5];
    const float* init_mv   = (const float*)d_in[6];
    const float* erase_w   = (const float*)d_in[7];
    const float* erase_b   = (const float*)d_in[8];
    const float* add_w     = (const float*)d_in[9];
    const float* add_b     = (const float*)d_in[10];
    const float* input_w   = (const float*)d_in[11];
    const float* input_b   = (const float*)d_in[12];
    const float* read_w    = (const float*)d_in[13];
    const float* read_b    = (const float*)d_in[14];
    const float* predict_w = (const float*)d_in[15];
    const float* predict_b = (const float*)d_in[16];

    float* ws  = (float*)d_ws;
    float* out = (float*)d_out;

    hipLaunchKernelGGL(prep_kernel, dim3(256), dim3(256), 0, stream,
                       erase_w, add_w, key_mem, input_w, read_w, ws);
    if (ws_size >= WS_NEED3) {
        hipLaunchKernelGGL(table_kernel, dim3(470), dim3(256), 0, stream,
                           q_embed, qa_embed, erase_b, add_b, input_b, read_b, 1, ws);
        hipLaunchKernelGGL(scan2_kernel, dim3(2048), dim3(256), 0, stream,
                           q_data, qa_data, init_mv, ws);
        hipLaunchKernelGGL(rce_kernel, dim3(4096), dim3(256), 0, stream,
                           q_data, target, predict_w, predict_b, ws, out);
        hipLaunchKernelGGL(finish_kernel, dim3(1), dim3(256), 0, stream, ws, out, 1);
    } else {
        hipLaunchKernelGGL(table_kernel, dim3(470), dim3(256), 0, stream,
                           q_embed, qa_embed, erase_b, add_b, input_b, read_b, 0, ws);
        hipLaunchKernelGGL(scan_kernel, dim3(BB), dim3(512), 0, stream,
                           q_data, qa_data, target, init_mv,
                           read_b, predict_w, predict_b, ws, out);
        hipLaunchKernelGGL(finish_kernel, dim3(1), dim3(256), 0, stream, ws, out, 0);
    }
}

// Round 10
// 543.155 us; speedup vs baseline: 2.7665x; 2.7665x over previous
//
#include <hip/hip_runtime.h>
#include <hip/hip_bf16.h>
#include <math.h>

#define BB 512
#define SS 512
#define MM 64
#define DK 128
#define DV 256
#define DF 128
#define CHUNK 16
#define NCHUNK (SS/CHUNK)

typedef __attribute__((ext_vector_type(8))) short s8v;            // 8 bf16
typedef __attribute__((ext_vector_type(4))) float f4v;            // MFMA acc
typedef __attribute__((ext_vector_type(8))) unsigned short u16x8; // 16B of bf16

#define MFMA16(a,b,c) __builtin_amdgcn_mfma_f32_16x16x32_bf16((a),(b),(c),0,0,0)

// ---- workspace layout ----
// ws[0..15] floats: loss accumulators (fallback paths). u16 pack region at byte 64:
#define EAP_OFF 0         // erase|add packed B-frags, N=512, K=256 (131072 u16)
#define KTP_OFF 131072    // key   packed, N=64,  K=128 (8192)
#define ITP_OFF 139264    // input packed, N=128, K=128 (16384)
#define RTP_OFF 155648    // read  packed, N=128, K=384 (49152) -> end 204800
// byte offsets from ws base:
#define WTAB_BYTE 409664                      // f32 [10001][64]   softmax'd w
#define IET_BYTE  2969920                     // bf16 [10001][128]: iet (fallback) OR riW2=ie@W2+read_b (fast path)
#define EAT_BYTE  5530176                     // bf16 [20001][512] sig(er)|tanh(ad)
#define WS_NEED2  26011200ull
#define READS_BYTE 26011264ull                // bf16 [512][512][256] read vectors
#define WS_NEED3  (READS_BYTE + (size_t)BB*SS*DV*2)
// loss partials: 2 f32 at the head of each rce block's (dead-after-stage) reads slice
#define PART_STRIDE_B 32768                   // 64 rows * 256 * 2B

__device__ __forceinline__ unsigned short f2bf(float x) {
    union { float f; unsigned u; } v; v.f = x;
    unsigned r = v.u + 0x7fffu + ((v.u >> 16) & 1u);
    return (unsigned short)(r >> 16);
}
__device__ __forceinline__ float bf2f(unsigned short h) {
    union { unsigned u; float f; } v; v.u = ((unsigned)h) << 16;
    return v.f;
}
__device__ __forceinline__ float u2f(unsigned u) {
    union { unsigned x; float f; } v; v.x = u; return v.f;
}
__device__ __forceinline__ float sigmoidf_(float x) { return 1.0f / (1.0f + __expf(-x)); }
__device__ __forceinline__ float fast_tanh(float x) {
    float e = __expf(2.0f * x);
    return 1.0f - 2.0f / (e + 1.0f);
}

// ======================= prep: pack weights =======================
__global__ void prep_kernel(const float* __restrict__ ew, const float* __restrict__ aw,
                            const float* __restrict__ km, const float* __restrict__ iw,
                            const float* __restrict__ rw, float* __restrict__ wsf) {
    int tid = blockIdx.x * 256 + threadIdx.x;
    int stride = gridDim.x * 256;
    if (tid < 2) wsf[tid] = 0.0f;
    unsigned short* bp = (unsigned short*)(wsf + 16);

    for (int i = tid; i < 131072; i += stride) {           // EAP: nf<32, ks<8
        int e = i & 7, l = (i >> 3) & 63, ks = (i >> 9) & 7, nf = i >> 12;
        int k = ks*32 + (l >> 4)*8 + e;
        int n = nf*16 + (l & 15);
        float v = (n < 256) ? ew[n*DV + k] : aw[(n-256)*DV + k];
        bp[EAP_OFF + i] = f2bf(v);
    }
    for (int i = tid; i < 8192; i += stride) {             // KTP
        int e = i & 7, l = (i >> 3) & 63, ks = (i >> 9) & 3, nf = i >> 11;
        int k = ks*32 + (l >> 4)*8 + e;
        int m = nf*16 + (l & 15);
        bp[KTP_OFF + i] = f2bf(km[m*DK + k]);
    }
    for (int i = tid; i < 16384; i += stride) {            // ITP
        int e = i & 7, l = (i >> 3) & 63, ks = (i >> 9) & 3, nf = i >> 11;
        int k = ks*32 + (l >> 4)*8 + e;
        int f = nf*16 + (l & 15);
        bp[ITP_OFF + i] = f2bf(iw[f*DK + k]);
    }
    for (int i = tid; i < 49152; i += stride) {            // RTP: nf<8, ks<12
        int e = i & 7, l = (i >> 3) & 63, g = i >> 9;
        int ks = g % 12, nf = g / 12;
        int j = ks*32 + (l >> 4)*8 + e;
        int f = nf*16 + (l & 15);
        bp[RTP_OFF + i] = f2bf(rw[f*(DV+DF) + j]);
    }
}

// ======================= table kernel =======================
// blocks [0,157): q-tables (wtab + {iet | riW2}); blocks [157,470): qa-tables (ea)
__launch_bounds__(256, 2)
__global__ void table_kernel(const float* __restrict__ q_embed, const float* __restrict__ qa_embed,
                             const float* __restrict__ erase_b, const float* __restrict__ add_b,
                             const float* __restrict__ input_b, const float* __restrict__ read_b,
                             int rw2flag, float* __restrict__ ws) {
    __shared__ __align__(128) char tsm[65536];
    const int tid  = threadIdx.x;
    const int lane = tid & 63;
    const int wave = tid >> 6;       // 0..3
    const int arow = lane & 15;
    const int ag   = lane >> 4;

    const unsigned short* wsb = (const unsigned short*)(ws + 16);
    const s8v* eap = (const s8v*)(wsb + EAP_OFF);
    const s8v* ktp = (const s8v*)(wsb + KTP_OFF);
    const s8v* itp = (const s8v*)(wsb + ITP_OFF);
    const s8v* rtp = (const s8v*)(wsb + RTP_OFF);
    float*          wtab = (float*)((char*)ws + WTAB_BYTE);
    unsigned short* iet  = (unsigned short*)((char*)ws + IET_BYTE);   // iet OR riW2 slot
    unsigned short* eat  = (unsigned short*)((char*)ws + EAT_BYTE);

    if (blockIdx.x < 157) {
        const int r0 = blockIdx.x * 64;
        char*  q16   = tsm;                    // [64][256B] bf16 swizzled
        float* sc    = (float*)(tsm + 16384);  // [64][68] f32
        unsigned short* iest = (unsigned short*)(tsm + 33792); // [64][128] linear

        #pragma unroll
        for (int it = 0; it < 8; ++it) {
            int u = it*256 + tid;
            int row = u >> 5, c4 = u & 31;
            int sr = r0 + row; if (sr > 10000) sr = 10000;
            float4 v = *(const float4*)(q_embed + sr*DK + c4*4);
            ushort4 p; p.x = f2bf(v.x); p.y = f2bf(v.y); p.z = f2bf(v.z); p.w = f2bf(v.w);
            *(ushort4*)(q16 + ((row*256 + c4*8) ^ ((row & 7) << 4))) = p;
        }
        __syncthreads();

        {
            s8v a[4];
            #pragma unroll
            for (int ks = 0; ks < 4; ++ks)
                a[ks] = *(const s8v*)(q16 + (((wave*16+arow)*256 + ks*64 + ag*16) ^ ((arow & 7) << 4)));
            #pragma unroll
            for (int j = 0; j < 4; ++j) {
                f4v cc = {0.f,0.f,0.f,0.f};
                #pragma unroll
                for (int ks = 0; ks < 4; ++ks) cc = MFMA16(a[ks], ktp[(j*4 + ks)*64 + lane], cc);
                #pragma unroll
                for (int r = 0; r < 4; ++r)
                    sc[(wave*16 + ag*4 + r)*68 + j*16 + arow] = cc[r];
            }
            __syncthreads();

            #pragma unroll
            for (int k = 0; k < 16; ++k) {
                int rr = wave*16 + k;
                float v = sc[rr*68 + lane];
                float mx = v;
                #pragma unroll
                for (int off = 32; off; off >>= 1) mx = fmaxf(mx, __shfl_xor(mx, off));
                float e = __expf(v - mx);
                float sum = e;
                #pragma unroll
                for (int off = 32; off; off >>= 1) sum += __shfl_xor(sum, off);
                if (r0 + rr < 10001) wtab[(r0 + rr)*64 + lane] = e / sum;
            }

            #pragma unroll
            for (int j = 0; j < 8; ++j) {                  // ie = tanh(q@Wi + ib) -> iest linear
                f4v cc = {0.f,0.f,0.f,0.f};
                #pragma unroll
                for (int ks = 0; ks < 4; ++ks) cc = MFMA16(a[ks], itp[(j*4 + ks)*64 + lane], cc);
                float bias = input_b[j*16 + arow];
                #pragma unroll
                for (int r = 0; r < 4; ++r)
                    iest[(wave*16 + ag*4 + r)*128 + j*16 + arow] = f2bf(fast_tanh(cc[r] + bias));
            }
        }
        __syncthreads();

        if (rw2flag) {
            // riW2 = iest @ W2 + read_b  (W2 = rtp ks 8..11), overwrite iest in place.
            s8v af2[4];
            #pragma unroll
            for (int ks2 = 0; ks2 < 4; ++ks2)
                af2[ks2] = *(const s8v*)((const char*)iest + (wave*16+arow)*256 + ks2*64 + ag*16);
            f4v acc2[8];
            #pragma unroll
            for (int j = 0; j < 8; ++j) acc2[j] = (f4v){0.f,0.f,0.f,0.f};
            #pragma unroll
            for (int ks2 = 0; ks2 < 4; ++ks2)
                #pragma unroll
                for (int j = 0; j < 8; ++j)
                    acc2[j] = MFMA16(af2[ks2], rtp[(j*12 + 8 + ks2)*64 + lane], acc2[j]);
            #pragma unroll
            for (int j = 0; j < 8; ++j) {
                float rb = read_b[j*16 + arow];
                #pragma unroll
                for (int r = 0; r < 4; ++r)
                    iest[(wave*16 + ag*4 + r)*128 + j*16 + arow] = f2bf(acc2[j][r] + rb);
            }
            __syncthreads();
        }
        #pragma unroll
        for (int it = 0; it < 4; ++it) {                   // coalesced store (iet or riW2)
            int u = it*256 + tid;
            int row = u >> 4, c8 = u & 15;
            if (r0 + row < 10001)
                *(u16x8*)(iet + (r0 + row)*128 + c8*8) = *(const u16x8*)(iest + row*128 + c8*8);
        }
    } else {
        const int r0 = (blockIdx.x - 157) * 64;
        char* qa16 = tsm;                                    // [64][512B] swizzled (32KB)
        unsigned short* east = (unsigned short*)(tsm + 32768); // [64][256] half-tile (32KB)

        #pragma unroll
        for (int it = 0; it < 16; ++it) {
            int u = it*256 + tid;
            int row = u >> 6, c4 = u & 63;
            int sr = r0 + row; if (sr > 20000) sr = 20000;
            float4 v = *(const float4*)(qa_embed + sr*DV + c4*4);
            ushort4 p; p.x = f2bf(v.x); p.y = f2bf(v.y); p.z = f2bf(v.z); p.w = f2bf(v.w);
            *(ushort4*)(qa16 + ((row*512 + c4*8) ^ ((row & 7) << 4))) = p;
        }
        __syncthreads();

        s8v af[8];
        #pragma unroll
        for (int ks = 0; ks < 8; ++ks)
            af[ks] = *(const s8v*)(qa16 + (((wave*16+arow)*512 + ks*64 + ag*16) ^ ((arow & 7) << 4)));

        for (int h = 0; h < 2; ++h) {                        // two n-halves of 256
            #pragma unroll
            for (int i = 0; i < 16; ++i) {
                int nt = h*16 + i;
                f4v cc = {0.f,0.f,0.f,0.f};
                #pragma unroll
                for (int ks = 0; ks < 8; ++ks) cc = MFMA16(af[ks], eap[(nt*8 + ks)*64 + lane], cc);
                int n = nt*16 + arow;
                float bias = (n < 256) ? erase_b[n] : add_b[n - 256];
                #pragma unroll
                for (int r = 0; r < 4; ++r) {
                    float v = cc[r] + bias;
                    float res = (n < 256) ? sigmoidf_(v) : fast_tanh(v);
                    east[(wave*16 + ag*4 + r)*256 + (n - h*256)] = f2bf(res);
                }
            }
            __syncthreads();
            #pragma unroll
            for (int it = 0; it < 8; ++it) {
                int u = it*256 + tid;
                int row = u >> 5, c8 = u & 31;
                if (r0 + row < 20001)
                    *(u16x8*)(eat + (size_t)(r0 + row)*512 + h*256 + c8*8) =
                        *(const u16x8*)(east + row*256 + c8*8);
            }
            __syncthreads();
        }
    }
}

// ======================= scan2: d-split recurrence =======================
// grid 2048 = 8 blocks/CU exactly. (256,4): VGPR cap 128, compiler lands at 64
// -> 8 waves/SIMD allowed by VGPR; LDS 17.4KB -> 9 blocks/CU. (256,8) forced
// VGPR=32 and spilled 4GB to scratch (round-9 regression) -- never again.
__launch_bounds__(256, 4)
__global__ void scan2_kernel(const int* __restrict__ q_data, const int* __restrict__ qa_data,
                             const float* __restrict__ init_mv,
                             float* __restrict__ ws) {
    __shared__ float          wf [CHUNK][68];     // softmax w rows (wave-uniform reads)
    __shared__ unsigned       eaL[CHUNK][68];     // interleaved e(lo)|a(hi) bf16 pairs per d
    __shared__ unsigned short rdp[CHUNK][4][68];  // bf16 read partials per m-quarter

    const int bid = blockIdx.x;
    const int xcd = bid & 7, idx = bid >> 3;
    const int b   = xcd*64 + (idx >> 2);
    const int dq  = idx & 3;
    const int tid = threadIdx.x;
    const int d   = tid & 63;
    const int mq  = tid >> 6;

    const float*          wtab  = (const float*)((const char*)ws + WTAB_BYTE);
    const unsigned short* eat   = (const unsigned short*)((const char*)ws + EAT_BYTE);
    unsigned short*       reads = (unsigned short*)((char*)ws + READS_BYTE);

    float mv[16];
    #pragma unroll
    for (int j = 0; j < 16; ++j) mv[j] = init_mv[(mq*16 + j)*DV + dq*64 + d];

    const int base = b * SS;
    const bool eaRole = (tid < 128);
    const int erow = tid >> 3;
    const int eu   = tid & 7;
    const int wrow = (tid - 128) >> 3;
    const int wu   = tid & 7;

    int ia0, iq0, ia1, iq1;
    u16x8 per, pad_; float4 pw0, pw1;

    auto loadidx = [&](int cc, int& xa, int& xq) {
        if (eaRole) xa = qa_data[base + cc*CHUNK + erow];
        else        xq = q_data [base + cc*CHUNK + wrow];
    };
    auto loadrows = [&]() {
        if (eaRole) {
            per  = *(const u16x8*)(eat + (size_t)ia0*512 +       dq*64 + eu*8);
            pad_ = *(const u16x8*)(eat + (size_t)ia0*512 + 256 + dq*64 + eu*8);
        } else {
            pw0 = *(const float4*)(wtab + iq0*64 + wu*8);
            pw1 = *(const float4*)(wtab + iq0*64 + wu*8 + 4);
        }
    };
    auto storerows = [&]() {
        if (eaRole) {
            unsigned pk[8];
            #pragma unroll
            for (int i = 0; i < 8; ++i)
                pk[i] = (unsigned)per[i] | ((unsigned)pad_[i] << 16);
            *(uint4*)&eaL[erow][eu*8]     = *(uint4*)&pk[0];
            *(uint4*)&eaL[erow][eu*8 + 4] = *(uint4*)&pk[4];
        } else {
            *(float4*)&wf[wrow][wu*8]     = pw0;
            *(float4*)&wf[wrow][wu*8 + 4] = pw1;
        }
    };

    loadidx(0, ia0, iq0);
    loadrows();
    loadidx(1, ia1, iq1);

    for (int c = 0; c < NCHUNK; ++c) {
        storerows();
        __syncthreads();                               // B1: staged
        ia0 = ia1; iq0 = iq1;
        if (c + 1 < NCHUNK) loadrows();
        { int c2 = (c + 2 < NCHUNK) ? c + 2 : NCHUNK - 1; loadidx(c2, ia1, iq1); }

        float4 wc0, wc1, wc2, wc3; unsigned eac;
        {
            const float4* wr = (const float4*)&wf[0][mq*16];
            wc0 = wr[0]; wc1 = wr[1]; wc2 = wr[2]; wc3 = wr[3];
            eac = eaL[0][d];
        }
        #pragma unroll
        for (int s = 0; s < CHUNK; ++s) {
            int sn = (s + 1 < CHUNK) ? s + 1 : s;
            const float4* wr = (const float4*)&wf[sn][mq*16];
            float4 wn0 = wr[0], wn1 = wr[1], wn2 = wr[2], wn3 = wr[3];
            unsigned ean = eaL[sn][d];

            float e = u2f(eac << 16);
            float a = u2f(eac & 0xffff0000u);
            float r0 = 0.f, r1 = 0.f, r2 = 0.f, r3 = 0.f;
            #define STEP(W, J) \
                r0 = fmaf(W.x, mv[J+0], r0); mv[J+0] = fmaf(W.x, fmaf(-mv[J+0], e, a), mv[J+0]); \
                r1 = fmaf(W.y, mv[J+1], r1); mv[J+1] = fmaf(W.y, fmaf(-mv[J+1], e, a), mv[J+1]); \
                r2 = fmaf(W.z, mv[J+2], r2); mv[J+2] = fmaf(W.z, fmaf(-mv[J+2], e, a), mv[J+2]); \
                r3 = fmaf(W.w, mv[J+3], r3); mv[J+3] = fmaf(W.w, fmaf(-mv[J+3], e, a), mv[J+3]);
            STEP(wc0, 0) STEP(wc1, 4) STEP(wc2, 8) STEP(wc3, 12)
            #undef STEP
            rdp[s][mq][d] = f2bf((r0 + r1) + (r2 + r3));

            wc0 = wn0; wc1 = wn1; wc2 = wn2; wc3 = wn3; eac = ean;
        }
        __syncthreads();                               // B2: partials in LDS

        {
            int s = tid >> 4, d0 = (tid & 15) * 4;
            float a0 = 0.f, a1 = 0.f, a2 = 0.f, a3 = 0.f;
            #pragma unroll
            for (int m2 = 0; m2 < 4; ++m2) {
                ushort4 v = *(const ushort4*)&rdp[s][m2][d0];
                a0 += bf2f(v.x); a1 += bf2f(v.y); a2 += bf2f(v.z); a3 += bf2f(v.w);
            }
            ushort4 o; o.x = f2bf(a0); o.y = f2bf(a1); o.z = f2bf(a2); o.w = f2bf(a3);
            *(ushort4*)(reads + (size_t)(base + c*CHUNK + s)*DV + dq*64 + d0) = o;
        }
    }
}

// ======================= rce kernel: [64][256]x[256][128] MFMA + riW2 + pred (atomic-free) =======================
__launch_bounds__(256, 2)
__global__ void rce_kernel(const int* __restrict__ q_data, const float* __restrict__ target,
                           const float* __restrict__ predict_w, const float* __restrict__ predict_b,
                           float* __restrict__ ws, float* __restrict__ out) {
    __shared__ __align__(128) char cat16[33792];        // [64][512B] swizzled; overlaid by rce_f [64][132] f32
    __shared__ __align__(16) unsigned short rw2s[64][128];
    __shared__ float lred[4][2];
    float* rce_f = (float*)cat16;

    const int blk  = blockIdx.x;
    const int b    = blk >> 3;
    const int s0   = (blk & 7) * 64;
    const int tid  = threadIdx.x;
    const int lane = tid & 63;
    const int wave = tid >> 6;
    const int arow = lane & 15;
    const int ag   = lane >> 4;

    const unsigned short* wsb   = (const unsigned short*)(ws + 16);
    const s8v*            rtp   = (const s8v*)(wsb + RTP_OFF);
    const unsigned short* rw2t  = (const unsigned short*)((const char*)ws + IET_BYTE);
    const unsigned short* reads = (const unsigned short*)((const char*)ws + READS_BYTE);

    #pragma unroll
    for (int it = 0; it < 8; ++it) {                 // stage reads -> cat (K=256)
        int u = it*256 + tid, row = u >> 5, cu = u & 31;
        u16x8 v = *(const u16x8*)(reads + (size_t)(b*SS + s0 + row)*DV + cu*8);
        *(u16x8*)(cat16 + ((row*512 + cu*16) ^ ((row & 7) << 4))) = v;
    }
    #pragma unroll
    for (int it = 0; it < 4; ++it) {                 // stage riW2 rows
        int u = it*256 + tid, row = u >> 4, cu = u & 15;
        int iq = q_data[b*SS + s0 + row];
        *(u16x8*)(&rw2s[row][cu*8]) = *(const u16x8*)(rw2t + (size_t)iq*128 + cu*8);
    }
    __syncthreads();

    f4v acc[8];
    #pragma unroll
    for (int n = 0; n < 8; ++n) acc[n] = (f4v){0.f,0.f,0.f,0.f};
    #pragma unroll
    for (int ks = 0; ks < 8; ++ks) {
        int row = wave*16 + arow;
        s8v a = *(const s8v*)(cat16 + ((row*512 + ks*64 + ag*16) ^ ((row & 7) << 4)));
        #pragma unroll
        for (int n = 0; n < 8; ++n)
            acc[n] = MFMA16(a, rtp[(n*12 + ks)*64 + lane], acc[n]);
    }
    __syncthreads();                                  // cat reads done before rce_f overlay

    #pragma unroll
    for (int n = 0; n < 8; ++n) {
        #pragma unroll
        for (int r = 0; r < 4; ++r) {
            int rr = wave*16 + ag*4 + r, col = n*16 + arow;
            rce_f[rr*132 + col] = fast_tanh(acc[n][r] + bf2f(rw2s[rr][col]));
        }
    }
    __syncthreads();

    const float pw_lo = predict_w[lane];
    const float pw_hi = predict_w[lane + 64];
    float local_loss = 0.f, local_cnt = 0.f;
    #pragma unroll
    for (int k = 0; k < 16; ++k) {
        int r = wave*16 + k;
        float p = fmaf(pw_lo, rce_f[r*132 + lane], pw_hi * rce_f[r*132 + 64 + lane]);
        #pragma unroll
        for (int off = 32; off; off >>= 1) p += __shfl_xor(p, off);
        if (lane == 0) {
            p += predict_b[0];
            int gi = b*SS + s0 + r;
            float t = target[gi];
            bool mask = t >= 0.0f;
            out[gi] = sigmoidf_(p);
            out[BB*SS + 1 + gi] = sigmoidf_(mask ? p : 0.0f);
            out[2*BB*SS + 1 + gi] = mask ? t : 0.0f;
            if (mask) {
                local_loss += fmaxf(p, 0.0f) - p*t + log1pf(__expf(-fabsf(p)));
                local_cnt  += 1.0f;
            }
        }
    }
    // atomic-free loss: block-reduce via LDS, store 1 pair into this block's dead reads slice
    if (lane == 0) { lred[wave][0] = local_loss; lred[wave][1] = local_cnt; }
    __syncthreads();
    if (tid == 0) {
        float L = lred[0][0] + lred[1][0] + lred[2][0] + lred[3][0];
        float C = lred[0][1] + lred[1][1] + lred[2][1] + lred[3][1];
        float* part = (float*)((char*)ws + READS_BYTE + (size_t)blk * PART_STRIDE_B);
        part[0] = L; part[1] = C;
    }
}

// ======================= finish: deterministic loss reduce =======================
__global__ void finish_kernel(float* __restrict__ ws, float* __restrict__ out, int mode) {
    if (mode == 0) {
        if (threadIdx.x == 0) out[BB*SS] = ws[0] / fmaxf(ws[1], 1.0f);
        return;
    }
    __shared__ float sl[4][2];
    const int tid = threadIdx.x, lane = tid & 63, wave = tid >> 6;
    const char* base = (const char*)ws + READS_BYTE;
    float L = 0.f, C = 0.f;
    for (int i = tid; i < 4096; i += 256) {
        const float* p = (const float*)(base + (size_t)i * PART_STRIDE_B);
        L += p[0]; C += p[1];
    }
    #pragma unroll
    for (int off = 32; off; off >>= 1) {
        L += __shfl_xor(L, off);
        C += __shfl_xor(C, off);
    }
    if (lane == 0) { sl[wave][0] = L; sl[wave][1] = C; }
    __syncthreads();
    if (tid == 0) {
        float LL = sl[0][0] + sl[1][0] + sl[2][0] + sl[3][0];
        float CC = sl[0][1] + sl[1][1] + sl[2][1] + sl[3][1];
        out[BB*SS] = LL / fmaxf(CC, 1.0f);
    }
}

// ======================= round-5 scan kernel (fallback, ws >= 26MB) =======================
__launch_bounds__(512, 2)
__global__ void scan_kernel(const int* __restrict__ q_data, const int* __restrict__ qa_data,
                            const float* __restrict__ target,
                            const float* __restrict__ init_mv,
                            const float* __restrict__ read_b,
                            const float* __restrict__ predict_w, const float* __restrict__ predict_b,
                            float* __restrict__ ws, float* __restrict__ out) {
    __shared__ __align__(128) char smem[50176];
    char*           cat16 = smem;
    float*          wf    = (float*)(smem + 12288);
    unsigned short* eaL   = (unsigned short*)(smem + 16640);
    unsigned short* rdp   = (unsigned short*)(smem + 33280);
    float*          rce_f = (float*)(smem + 41728);

    const int b    = blockIdx.x;
    const int tid  = threadIdx.x;
    const int lane = tid & 63;
    const int wave = tid >> 6;
    const int arow = lane & 15;
    const int ag   = lane >> 4;
    const int d    = tid & 255;
    const int half = tid >> 8;

    const unsigned short* wsb = (const unsigned short*)(ws + 16);
    const s8v* rtp = (const s8v*)(wsb + RTP_OFF);
    const float*          wtab = (const float*)((const char*)ws + WTAB_BYTE);
    const unsigned short* iet  = (const unsigned short*)((const char*)ws + IET_BYTE);
    const unsigned short* eat  = (const unsigned short*)((const char*)ws + EAT_BYTE);

    float mv[32];
    #pragma unroll
    for (int i = 0; i < 32; ++i) mv[i] = init_mv[(half*32 + i)*DV + d];

    const float rb    = read_b[wave*16 + arow];
    const float pw_lo = predict_w[lane];
    const float pw_hi = predict_w[lane + 64];

    const int base  = b * SS;
    const int erow  = tid >> 5;
    const int eunit = tid & 31;
    const int role  = tid >> 8;
    const int grow  = (tid >> 4) & 15;
    const int gunit = tid & 15;

    int iqa0, iq0, iqa1, iq1;
    u16x8 pe0, pe1, pie;
    float4 pwf;

    auto loadidx = [&](int cc, int& xa, int& xq) {
        xa = qa_data[base + cc*CHUNK + erow];
        xq = q_data [base + cc*CHUNK + grow];
    };
    auto loadrows = [&]() {
        const unsigned short* er_ptr = eat + (size_t)iqa0*512 + eunit*16;
        pe0 = *(const u16x8*)(er_ptr);
        pe1 = *(const u16x8*)(er_ptr + 8);
        if (role == 0) pwf = *(const float4*)(wtab + iq0*64 + gunit*4);
        else           pie = *(const u16x8*)(iet + (size_t)iq0*128 + gunit*8);
    };
    auto storerows = [&]() {
        *(u16x8*)(eaL + erow*520 + eunit*16)     = pe0;
        *(u16x8*)(eaL + erow*520 + eunit*16 + 8) = pe1;
        if (role == 0) *(float4*)((char*)wf + grow*272 + gunit*16) = pwf;
        else *(u16x8*)(cat16 + ((grow*768 + 512 + gunit*16) ^ ((grow & 7) << 4))) = pie;
    };

    loadidx(0, iqa0, iq0);
    loadrows();
    loadidx(1, iqa1, iq1);

    float local_loss = 0.0f, local_cnt = 0.0f;

    for (int c = 0; c < NCHUNK; ++c) {
        storerows();
        __syncthreads();
        iqa0 = iqa1; iq0 = iq1;
        if (c + 1 < NCHUNK) loadrows();
        { int c2 = (c + 2 < NCHUNK) ? c + 2 : NCHUNK - 1; loadidx(c2, iqa1, iq1); }

        for (int s = 0; s < CHUNK; ++s) {
            float e = bf2f(eaL[s*520 + d]);
            float a = bf2f(eaL[s*520 + 256 + d]);
            const float4* wr4 = (const float4*)(wf + s*68 + half*32);
            float r0 = 0.f, r1 = 0.f, r2 = 0.f, r3 = 0.f;
            #pragma unroll
            for (int j = 0; j < 8; ++j) {
                float4 w = wr4[j];
                r0 = fmaf(w.x, mv[j*4+0], r0); mv[j*4+0] = fmaf(w.x, fmaf(-mv[j*4+0], e, a), mv[j*4+0]);
                r1 = fmaf(w.y, mv[j*4+1], r1); mv[j*4+1] = fmaf(w.y, fmaf(-mv[j*4+1], e, a), mv[j*4+1]);
                r2 = fmaf(w.z, mv[j*4+2], r2); mv[j*4+2] = fmaf(w.z, fmaf(-mv[j*4+2], e, a), mv[j*4+2]);
                r3 = fmaf(w.w, mv[j*4+3], r3); mv[j*4+3] = fmaf(w.w, fmaf(-mv[j*4+3], e, a), mv[j*4+3]);
            }
            float rd = (r0 + r1) + (r2 + r3);
            if (half == 0) {
                *(unsigned short*)(cat16 + ((s*768 + d*2) ^ ((s & 7) << 4))) = f2bf(rd);
            } else {
                rdp[s*264 + d] = f2bf(rd);
            }
        }
        __syncthreads();

        if (half == 0) {
            #pragma unroll
            for (int s = 0; s < CHUNK; ++s) {
                unsigned short* p = (unsigned short*)(cat16 + ((s*768 + d*2) ^ ((s & 7) << 4)));
                *p = f2bf(bf2f(*p) + bf2f(rdp[s*264 + d]));
            }
        }
        __syncthreads();

        {
            f4v cc = {0.f,0.f,0.f,0.f};
            #pragma unroll
            for (int ks = 0; ks < 12; ++ks) {
                s8v a = *(const s8v*)(cat16 + ((arow*768 + ks*64 + ag*16) ^ ((arow & 7) << 4)));
                cc = MFMA16(a, rtp[(wave*12 + ks)*64 + lane], cc);
            }
            #pragma unroll
            for (int r = 0; r < 4; ++r)
                rce_f[(ag*4 + r)*132 + wave*16 + arow] = fast_tanh(cc[r] + rb);
        }
        __syncthreads();

        #pragma unroll
        for (int k = 0; k < 2; ++k) {
            int r = wave*2 + k;
            float p = fmaf(pw_lo, rce_f[r*132 + lane], pw_hi * rce_f[r*132 + 64 + lane]);
            #pragma unroll
            for (int off = 32; off; off >>= 1) p += __shfl_xor(p, off);
            if (lane == 0) {
                p += predict_b[0];
                int gi = b*SS + c*CHUNK + r;
                float t = target[gi];
                bool mask = t >= 0.0f;
                out[gi] = sigmoidf_(p);
                float pm = mask ? p : 0.0f;
                out[BB*SS + 1 + gi] = sigmoidf_(pm);
                out[2*BB*SS + 1 + gi] = mask ? t : 0.0f;
                if (mask) {
                    local_loss += fmaxf(p, 0.0f) - p*t + log1pf(__expf(-fabsf(p)));
                    local_cnt  += 1.0f;
                }
            }
        }
    }

    #pragma unroll
    for (int off = 32; off; off >>= 1) {
        local_loss += __shfl_xor(local_loss, off);
        local_cnt  += __shfl_xor(local_cnt, off);
    }
    if (lane == 0) {
        atomicAdd(&ws[0], local_loss);
        atomicAdd(&ws[1], local_cnt);
    }
}

extern "C" void kernel_launch(void* const* d_in, const int* in_sizes, int n_in,
                              void* d_out, int out_size, void* d_ws, size_t ws_size,
                              hipStream_t stream) {
    const int*   q_data    = (const int*)d_in[0];
    const int*   qa_data   = (const int*)d_in[1];
    const float* target    = (const float*)d_in[2];
    const float* q_embed   = (const float*)d_in[3];
    const float* qa_embed  = (const float*)d_in[4];
    const float* key_mem   = (const float*)d_in[5];
    const float* init_mv   = (const float*)d_in[6];
    const float* erase_w   = (const float*)d_in[7];
    const float* erase_b   = (const float*)d_in[8];
    const float* add_w     = (const float*)d_in[9];
    const float* add_b     = (const float*)d_in[10];
    const float* input_w   = (const float*)d_in[11];
    const float* input_b   = (const float*)d_in[12];
    const float* read_w    = (const float*)d_in[13];
    const float* read_b    = (const float*)d_in[14];
    const float* predict_w = (const float*)d_in[15];
    const float* predict_b = (const float*)d_in[16];

    float* ws  = (float*)d_ws;
    float* out = (float*)d_out;

    hipLaunchKernelGGL(prep_kernel, dim3(256), dim3(256), 0, stream,
                       erase_w, add_w, key_mem, input_w, read_w, ws);
    if (ws_size >= WS_NEED3) {
        hipLaunchKernelGGL(table_kernel, dim3(470), dim3(256), 0, stream,
                           q_embed, qa_embed, erase_b, add_b, input_b, read_b, 1, ws);
        hipLaunchKernelGGL(scan2_kernel, dim3(2048), dim3(256), 0, stream,
                           q_data, qa_data, init_mv, ws);
        hipLaunchKernelGGL(rce_kernel, dim3(4096), dim3(256), 0, stream,
                           q_data, target, predict_w, predict_b, ws, out);
        hipLaunchKernelGGL(finish_kernel, dim3(1), dim3(256), 0, stream, ws, out, 1);
    } else {
        hipLaunchKernelGGL(table_kernel, dim3(470), dim3(256), 0, stream,
                           q_embed, qa_embed, erase_b, add_b, input_b, read_b, 0, ws);
        hipLaunchKernelGGL(scan_kernel, dim3(BB), dim3(512), 0, stream,
                           q_data, qa_data, target, init_mv,
                           read_b, predict_w, predict_b, ws, out);
        hipLaunchKernelGGL(finish_kernel, dim3(1), dim3(256), 0, stream, ws, out, 0);
    }
}

// Round 11
// 527.398 us; speedup vs baseline: 2.8492x; 1.0299x over previous
//
#include <hip/hip_runtime.h>
#include <hip/hip_bf16.h>
#include <math.h>

#define BB 512
#define SS 512
#define MM 64
#define DK 128
#define DV 256
#define DF 128
#define CHUNK 16
#define NCHUNK (SS/CHUNK)

typedef __attribute__((ext_vector_type(8))) short s8v;            // 8 bf16
typedef __attribute__((ext_vector_type(4))) float f4v;            // MFMA acc
typedef __attribute__((ext_vector_type(2))) float f2v;            // packed f32 pair
typedef __attribute__((ext_vector_type(8))) unsigned short u16x8; // 16B of bf16

#define MFMA16(a,b,c) __builtin_amdgcn_mfma_f32_16x16x32_bf16((a),(b),(c),0,0,0)

// ---- workspace layout ----
// ws[0..15] floats: loss accumulators (fallback paths). u16 pack region at byte 64:
#define EAP_OFF 0         // erase|add packed B-frags, N=512, K=256 (131072 u16)
#define KTP_OFF 131072    // key   packed, N=64,  K=128 (8192)
#define ITP_OFF 139264    // input packed, N=128, K=128 (16384)
#define RTP_OFF 155648    // read  packed, N=128, K=384 (49152) -> end 204800
// byte offsets from ws base:
#define WTAB_BYTE 409664                      // f32 [10001][64]   softmax'd w
#define IET_BYTE  2969920                     // bf16 [10001][128]: iet (fallback) OR riW2=ie@W2+read_b (fast path)
#define EAT_BYTE  5530176                     // bf16 [20001][512] sig(er)|tanh(ad)
#define WS_NEED2  26011200ull
#define READS_BYTE 26011264ull                // bf16 [512][512][256] read vectors
#define WS_NEED3  (READS_BYTE + (size_t)BB*SS*DV*2)
// loss partials: 2 f32 at the head of each rce block's (dead-after-stage) reads slice
#define PART_STRIDE_B 32768                   // 64 rows * 256 * 2B

__device__ __forceinline__ unsigned short f2bf(float x) {
    union { float f; unsigned u; } v; v.f = x;
    unsigned r = v.u + 0x7fffu + ((v.u >> 16) & 1u);
    return (unsigned short)(r >> 16);
}
__device__ __forceinline__ float bf2f(unsigned short h) {
    union { unsigned u; float f; } v; v.u = ((unsigned)h) << 16;
    return v.f;
}
__device__ __forceinline__ float u2f(unsigned u) {
    union { unsigned x; float f; } v; v.x = u; return v.f;
}
__device__ __forceinline__ float sigmoidf_(float x) { return 1.0f / (1.0f + __expf(-x)); }
__device__ __forceinline__ float fast_tanh(float x) {
    float e = __expf(2.0f * x);
    return 1.0f - 2.0f / (e + 1.0f);
}

// ======================= prep: pack weights =======================
__global__ void prep_kernel(const float* __restrict__ ew, const float* __restrict__ aw,
                            const float* __restrict__ km, const float* __restrict__ iw,
                            const float* __restrict__ rw, float* __restrict__ wsf) {
    int tid = blockIdx.x * 256 + threadIdx.x;
    int stride = gridDim.x * 256;
    if (tid < 2) wsf[tid] = 0.0f;
    unsigned short* bp = (unsigned short*)(wsf + 16);

    for (int i = tid; i < 131072; i += stride) {           // EAP: nf<32, ks<8
        int e = i & 7, l = (i >> 3) & 63, ks = (i >> 9) & 7, nf = i >> 12;
        int k = ks*32 + (l >> 4)*8 + e;
        int n = nf*16 + (l & 15);
        float v = (n < 256) ? ew[n*DV + k] : aw[(n-256)*DV + k];
        bp[EAP_OFF + i] = f2bf(v);
    }
    for (int i = tid; i < 8192; i += stride) {             // KTP
        int e = i & 7, l = (i >> 3) & 63, ks = (i >> 9) & 3, nf = i >> 11;
        int k = ks*32 + (l >> 4)*8 + e;
        int m = nf*16 + (l & 15);
        bp[KTP_OFF + i] = f2bf(km[m*DK + k]);
    }
    for (int i = tid; i < 16384; i += stride) {            // ITP
        int e = i & 7, l = (i >> 3) & 63, ks = (i >> 9) & 3, nf = i >> 11;
        int k = ks*32 + (l >> 4)*8 + e;
        int f = nf*16 + (l & 15);
        bp[ITP_OFF + i] = f2bf(iw[f*DK + k]);
    }
    for (int i = tid; i < 49152; i += stride) {            // RTP: nf<8, ks<12
        int e = i & 7, l = (i >> 3) & 63, g = i >> 9;
        int ks = g % 12, nf = g / 12;
        int j = ks*32 + (l >> 4)*8 + e;
        int f = nf*16 + (l & 15);
        bp[RTP_OFF + i] = f2bf(rw[f*(DV+DF) + j]);
    }
}

// ======================= table kernel =======================
// blocks [0,157): q-tables (wtab + {iet | riW2}); blocks [157,470): qa-tables (ea)
__launch_bounds__(256, 2)
__global__ void table_kernel(const float* __restrict__ q_embed, const float* __restrict__ qa_embed,
                             const float* __restrict__ erase_b, const float* __restrict__ add_b,
                             const float* __restrict__ input_b, const float* __restrict__ read_b,
                             int rw2flag, float* __restrict__ ws) {
    __shared__ __align__(128) char tsm[65536];
    const int tid  = threadIdx.x;
    const int lane = tid & 63;
    const int wave = tid >> 6;       // 0..3
    const int arow = lane & 15;
    const int ag   = lane >> 4;

    const unsigned short* wsb = (const unsigned short*)(ws + 16);
    const s8v* eap = (const s8v*)(wsb + EAP_OFF);
    const s8v* ktp = (const s8v*)(wsb + KTP_OFF);
    const s8v* itp = (const s8v*)(wsb + ITP_OFF);
    const s8v* rtp = (const s8v*)(wsb + RTP_OFF);
    float*          wtab = (float*)((char*)ws + WTAB_BYTE);
    unsigned short* iet  = (unsigned short*)((char*)ws + IET_BYTE);   // iet OR riW2 slot
    unsigned short* eat  = (unsigned short*)((char*)ws + EAT_BYTE);

    if (blockIdx.x < 157) {
        const int r0 = blockIdx.x * 64;
        char*  q16   = tsm;                    // [64][256B] bf16 swizzled
        float* sc    = (float*)(tsm + 16384);  // [64][68] f32
        unsigned short* iest = (unsigned short*)(tsm + 33792); // [64][128] linear

        #pragma unroll
        for (int it = 0; it < 8; ++it) {
            int u = it*256 + tid;
            int row = u >> 5, c4 = u & 31;
            int sr = r0 + row; if (sr > 10000) sr = 10000;
            float4 v = *(const float4*)(q_embed + sr*DK + c4*4);
            ushort4 p; p.x = f2bf(v.x); p.y = f2bf(v.y); p.z = f2bf(v.z); p.w = f2bf(v.w);
            *(ushort4*)(q16 + ((row*256 + c4*8) ^ ((row & 7) << 4))) = p;
        }
        __syncthreads();

        {
            s8v a[4];
            #pragma unroll
            for (int ks = 0; ks < 4; ++ks)
                a[ks] = *(const s8v*)(q16 + (((wave*16+arow)*256 + ks*64 + ag*16) ^ ((arow & 7) << 4)));
            #pragma unroll
            for (int j = 0; j < 4; ++j) {
                f4v cc = {0.f,0.f,0.f,0.f};
                #pragma unroll
                for (int ks = 0; ks < 4; ++ks) cc = MFMA16(a[ks], ktp[(j*4 + ks)*64 + lane], cc);
                #pragma unroll
                for (int r = 0; r < 4; ++r)
                    sc[(wave*16 + ag*4 + r)*68 + j*16 + arow] = cc[r];
            }
            __syncthreads();

            #pragma unroll
            for (int k = 0; k < 16; ++k) {
                int rr = wave*16 + k;
                float v = sc[rr*68 + lane];
                float mx = v;
                #pragma unroll
                for (int off = 32; off; off >>= 1) mx = fmaxf(mx, __shfl_xor(mx, off));
                float e = __expf(v - mx);
                float sum = e;
                #pragma unroll
                for (int off = 32; off; off >>= 1) sum += __shfl_xor(sum, off);
                if (r0 + rr < 10001) wtab[(r0 + rr)*64 + lane] = e / sum;
            }

            #pragma unroll
            for (int j = 0; j < 8; ++j) {                  // ie = tanh(q@Wi + ib) -> iest linear
                f4v cc = {0.f,0.f,0.f,0.f};
                #pragma unroll
                for (int ks = 0; ks < 4; ++ks) cc = MFMA16(a[ks], itp[(j*4 + ks)*64 + lane], cc);
                float bias = input_b[j*16 + arow];
                #pragma unroll
                for (int r = 0; r < 4; ++r)
                    iest[(wave*16 + ag*4 + r)*128 + j*16 + arow] = f2bf(fast_tanh(cc[r] + bias));
            }
        }
        __syncthreads();

        if (rw2flag) {
            // riW2 = iest @ W2 + read_b  (W2 = rtp ks 8..11), overwrite iest in place.
            s8v af2[4];
            #pragma unroll
            for (int ks2 = 0; ks2 < 4; ++ks2)
                af2[ks2] = *(const s8v*)((const char*)iest + (wave*16+arow)*256 + ks2*64 + ag*16);
            f4v acc2[8];
            #pragma unroll
            for (int j = 0; j < 8; ++j) acc2[j] = (f4v){0.f,0.f,0.f,0.f};
            #pragma unroll
            for (int ks2 = 0; ks2 < 4; ++ks2)
                #pragma unroll
                for (int j = 0; j < 8; ++j)
                    acc2[j] = MFMA16(af2[ks2], rtp[(j*12 + 8 + ks2)*64 + lane], acc2[j]);
            #pragma unroll
            for (int j = 0; j < 8; ++j) {
                float rb = read_b[j*16 + arow];
                #pragma unroll
                for (int r = 0; r < 4; ++r)
                    iest[(wave*16 + ag*4 + r)*128 + j*16 + arow] = f2bf(acc2[j][r] + rb);
            }
            __syncthreads();
        }
        #pragma unroll
        for (int it = 0; it < 4; ++it) {                   // coalesced store (iet or riW2)
            int u = it*256 + tid;
            int row = u >> 4, c8 = u & 15;
            if (r0 + row < 10001)
                *(u16x8*)(iet + (r0 + row)*128 + c8*8) = *(const u16x8*)(iest + row*128 + c8*8);
        }
    } else {
        const int r0 = (blockIdx.x - 157) * 64;
        char* qa16 = tsm;                                    // [64][512B] swizzled (32KB)
        unsigned short* east = (unsigned short*)(tsm + 32768); // [64][256] half-tile (32KB)

        #pragma unroll
        for (int it = 0; it < 16; ++it) {
            int u = it*256 + tid;
            int row = u >> 6, c4 = u & 63;
            int sr = r0 + row; if (sr > 20000) sr = 20000;
            float4 v = *(const float4*)(qa_embed + sr*DV + c4*4);
            ushort4 p; p.x = f2bf(v.x); p.y = f2bf(v.y); p.z = f2bf(v.z); p.w = f2bf(v.w);
            *(ushort4*)(qa16 + ((row*512 + c4*8) ^ ((row & 7) << 4))) = p;
        }
        __syncthreads();

        s8v af[8];
        #pragma unroll
        for (int ks = 0; ks < 8; ++ks)
            af[ks] = *(const s8v*)(qa16 + (((wave*16+arow)*512 + ks*64 + ag*16) ^ ((arow & 7) << 4)));

        for (int h = 0; h < 2; ++h) {                        // two n-halves of 256
            #pragma unroll
            for (int i = 0; i < 16; ++i) {
                int nt = h*16 + i;
                f4v cc = {0.f,0.f,0.f,0.f};
                #pragma unroll
                for (int ks = 0; ks < 8; ++ks) cc = MFMA16(af[ks], eap[(nt*8 + ks)*64 + lane], cc);
                int n = nt*16 + arow;
                float bias = (n < 256) ? erase_b[n] : add_b[n - 256];
                #pragma unroll
                for (int r = 0; r < 4; ++r) {
                    float v = cc[r] + bias;
                    float res = (n < 256) ? sigmoidf_(v) : fast_tanh(v);
                    east[(wave*16 + ag*4 + r)*256 + (n - h*256)] = f2bf(res);
                }
            }
            __syncthreads();
            #pragma unroll
            for (int it = 0; it < 8; ++it) {
                int u = it*256 + tid;
                int row = u >> 5, c8 = u & 31;
                if (r0 + row < 20001)
                    *(u16x8*)(eat + (size_t)(r0 + row)*512 + h*256 + c8*8) =
                        *(const u16x8*)(east + row*256 + c8*8);
            }
            __syncthreads();
        }
    }
}

// ======================= scan2: d-split recurrence, pk-f32 + low-VGPR =======================
// grid 2048 = 8 blocks/CU of work. VGPR history: (256,8) forced 32 -> 4GB spill
// (round 9); (256,4) with reg-pipeline landed 64 -> waves/CU HALVES at vgpr=64
// (m69), only ~4 blocks/CU resident (rounds 8/10 identical despite LDS change).
// This version drops the w double-buffer (saves 17 regs) targeting <64 VGPR,
// and uses float2 + elementwise_fma so LLVM emits v_pk_fma_f32 (half the issue
// slots for the 48-FMA chain).
__launch_bounds__(256, 4)
__global__ void scan2_kernel(const int* __restrict__ q_data, const int* __restrict__ qa_data,
                             const float* __restrict__ init_mv,
                             float* __restrict__ ws) {
    __shared__ float          wf [CHUNK][68];     // softmax w rows (wave-uniform reads)
    __shared__ unsigned       eaL[CHUNK][68];     // interleaved e(lo)|a(hi) bf16 pairs per d
    __shared__ unsigned short rdp[CHUNK][4][68];  // bf16 read partials per m-quarter

    const int bid = blockIdx.x;
    const int xcd = bid & 7, idx = bid >> 3;
    const int b   = xcd*64 + (idx >> 2);
    const int dq  = idx & 3;
    const int tid = threadIdx.x;
    const int d   = tid & 63;
    const int mq  = tid >> 6;

    const float*          wtab  = (const float*)((const char*)ws + WTAB_BYTE);
    const unsigned short* eat   = (const unsigned short*)((const char*)ws + EAT_BYTE);
    unsigned short*       reads = (unsigned short*)((char*)ws + READS_BYTE);

    f2v mv2[8];
    #pragma unroll
    for (int j = 0; j < 8; ++j) {
        mv2[j][0] = init_mv[(mq*16 + 2*j    )*DV + dq*64 + d];
        mv2[j][1] = init_mv[(mq*16 + 2*j + 1)*DV + dq*64 + d];
    }

    const int base = b * SS;
    const bool eaRole = (tid < 128);
    const int erow = tid >> 3;
    const int eu   = tid & 7;
    const int wrow = (tid - 128) >> 3;
    const int wu   = tid & 7;

    int ia0, iq0, ia1, iq1;
    u16x8 per, pad_; float4 pw0, pw1;

    auto loadidx = [&](int cc, int& xa, int& xq) {
        if (eaRole) xa = qa_data[base + cc*CHUNK + erow];
        else        xq = q_data [base + cc*CHUNK + wrow];
    };
    auto loadrows = [&]() {
        if (eaRole) {
            per  = *(const u16x8*)(eat + (size_t)ia0*512 +       dq*64 + eu*8);
            pad_ = *(const u16x8*)(eat + (size_t)ia0*512 + 256 + dq*64 + eu*8);
        } else {
            pw0 = *(const float4*)(wtab + iq0*64 + wu*8);
            pw1 = *(const float4*)(wtab + iq0*64 + wu*8 + 4);
        }
    };
    auto storerows = [&]() {
        if (eaRole) {
            unsigned pk[8];
            #pragma unroll
            for (int i = 0; i < 8; ++i)
                pk[i] = (unsigned)per[i] | ((unsigned)pad_[i] << 16);
            *(uint4*)&eaL[erow][eu*8]     = *(uint4*)&pk[0];
            *(uint4*)&eaL[erow][eu*8 + 4] = *(uint4*)&pk[4];
        } else {
            *(float4*)&wf[wrow][wu*8]     = pw0;
            *(float4*)&wf[wrow][wu*8 + 4] = pw1;
        }
    };

    loadidx(0, ia0, iq0);
    loadrows();
    loadidx(1, ia1, iq1);

    for (int c = 0; c < NCHUNK; ++c) {
        storerows();
        __syncthreads();                               // B1: staged
        ia0 = ia1; iq0 = iq1;
        if (c + 1 < NCHUNK) loadrows();
        { int c2 = (c + 2 < NCHUNK) ? c + 2 : NCHUNK - 1; loadidx(c2, ia1, iq1); }

        #pragma unroll
        for (int s = 0; s < CHUNK; ++s) {
            unsigned eac = eaL[s][d];
            float e = u2f(eac << 16);
            float a = u2f(eac & 0xffff0000u);
            f2v e2; e2[0] = e; e2[1] = e;
            f2v a2; a2[0] = a; a2[1] = a;
            const f2v* wr = (const f2v*)&wf[s][mq*16];   // wave-uniform broadcast
            f2v r0 = {0.f, 0.f}, r1 = {0.f, 0.f};
            #pragma unroll
            for (int j = 0; j < 8; j += 2) {
                f2v w0 = wr[j], w1 = wr[j+1];
                r0 = __builtin_elementwise_fma(w0, mv2[j], r0);
                mv2[j] = __builtin_elementwise_fma(
                    w0, __builtin_elementwise_fma(-mv2[j], e2, a2), mv2[j]);
                r1 = __builtin_elementwise_fma(w1, mv2[j+1], r1);
                mv2[j+1] = __builtin_elementwise_fma(
                    w1, __builtin_elementwise_fma(-mv2[j+1], e2, a2), mv2[j+1]);
            }
            f2v rs = r0 + r1;
            rdp[s][mq][d] = f2bf(rs[0] + rs[1]);
        }
        __syncthreads();                               // B2: partials in LDS

        {
            int s = tid >> 4, d0 = (tid & 15) * 4;
            float a0 = 0.f, a1 = 0.f, a2 = 0.f, a3 = 0.f;
            #pragma unroll
            for (int m2 = 0; m2 < 4; ++m2) {
                ushort4 v = *(const ushort4*)&rdp[s][m2][d0];
                a0 += bf2f(v.x); a1 += bf2f(v.y); a2 += bf2f(v.z); a3 += bf2f(v.w);
            }
            ushort4 o; o.x = f2bf(a0); o.y = f2bf(a1); o.z = f2bf(a2); o.w = f2bf(a3);
            *(ushort4*)(reads + (size_t)(base + c*CHUNK + s)*DV + dq*64 + d0) = o;
        }
    }
}

// ======================= rce kernel: [64][256]x[256][128] MFMA + riW2 + pred (atomic-free) =======================
__launch_bounds__(256, 2)
__global__ void rce_kernel(const int* __restrict__ q_data, const float* __restrict__ target,
                           const float* __restrict__ predict_w, const float* __restrict__ predict_b,
                           float* __restrict__ ws, float* __restrict__ out) {
    __shared__ __align__(128) char cat16[33792];        // [64][512B] swizzled; overlaid by rce_f [64][132] f32
    __shared__ __align__(16) unsigned short rw2s[64][128];
    __shared__ float lred[4][2];
    float* rce_f = (float*)cat16;

    const int blk  = blockIdx.x;
    const int b    = blk >> 3;
    const int s0   = (blk & 7) * 64;
    const int tid  = threadIdx.x;
    const int lane = tid & 63;
    const int wave = tid >> 6;
    const int arow = lane & 15;
    const int ag   = lane >> 4;

    const unsigned short* wsb   = (const unsigned short*)(ws + 16);
    const s8v*            rtp   = (const s8v*)(wsb + RTP_OFF);
    const unsigned short* rw2t  = (const unsigned short*)((const char*)ws + IET_BYTE);
    const unsigned short* reads = (const unsigned short*)((const char*)ws + READS_BYTE);

    #pragma unroll
    for (int it = 0; it < 8; ++it) {                 // stage reads -> cat (K=256)
        int u = it*256 + tid, row = u >> 5, cu = u & 31;
        u16x8 v = *(const u16x8*)(reads + (size_t)(b*SS + s0 + row)*DV + cu*8);
        *(u16x8*)(cat16 + ((row*512 + cu*16) ^ ((row & 7) << 4))) = v;
    }
    #pragma unroll
    for (int it = 0; it < 4; ++it) {                 // stage riW2 rows
        int u = it*256 + tid, row = u >> 4, cu = u & 15;
        int iq = q_data[b*SS + s0 + row];
        *(u16x8*)(&rw2s[row][cu*8]) = *(const u16x8*)(rw2t + (size_t)iq*128 + cu*8);
    }
    __syncthreads();

    f4v acc[8];
    #pragma unroll
    for (int n = 0; n < 8; ++n) acc[n] = (f4v){0.f,0.f,0.f,0.f};
    #pragma unroll
    for (int ks = 0; ks < 8; ++ks) {
        int row = wave*16 + arow;
        s8v a = *(const s8v*)(cat16 + ((row*512 + ks*64 + ag*16) ^ ((row & 7) << 4)));
        #pragma unroll
        for (int n = 0; n < 8; ++n)
            acc[n] = MFMA16(a, rtp[(n*12 + ks)*64 + lane], acc[n]);
    }
    __syncthreads();                                  // cat reads done before rce_f overlay

    #pragma unroll
    for (int n = 0; n < 8; ++n) {
        #pragma unroll
        for (int r = 0; r < 4; ++r) {
            int rr = wave*16 + ag*4 + r, col = n*16 + arow;
            rce_f[rr*132 + col] = fast_tanh(acc[n][r] + bf2f(rw2s[rr][col]));
        }
    }
    __syncthreads();

    const float pw_lo = predict_w[lane];
    const float pw_hi = predict_w[lane + 64];
    float local_loss = 0.f, local_cnt = 0.f;
    #pragma unroll
    for (int k = 0; k < 16; ++k) {
        int r = wave*16 + k;
        float p = fmaf(pw_lo, rce_f[r*132 + lane], pw_hi * rce_f[r*132 + 64 + lane]);
        #pragma unroll
        for (int off = 32; off; off >>= 1) p += __shfl_xor(p, off);
        if (lane == 0) {
            p += predict_b[0];
            int gi = b*SS + s0 + r;
            float t = target[gi];
            bool mask = t >= 0.0f;
            out[gi] = sigmoidf_(p);
            out[BB*SS + 1 + gi] = sigmoidf_(mask ? p : 0.0f);
            out[2*BB*SS + 1 + gi] = mask ? t : 0.0f;
            if (mask) {
                local_loss += fmaxf(p, 0.0f) - p*t + log1pf(__expf(-fabsf(p)));
                local_cnt  += 1.0f;
            }
        }
    }
    // atomic-free loss: block-reduce via LDS, store 1 pair into this block's dead reads slice
    if (lane == 0) { lred[wave][0] = local_loss; lred[wave][1] = local_cnt; }
    __syncthreads();
    if (tid == 0) {
        float L = lred[0][0] + lred[1][0] + lred[2][0] + lred[3][0];
        float C = lred[0][1] + lred[1][1] + lred[2][1] + lred[3][1];
        float* part = (float*)((char*)ws + READS_BYTE + (size_t)blk * PART_STRIDE_B);
        part[0] = L; part[1] = C;
    }
}

// ======================= finish: deterministic loss reduce =======================
__global__ void finish_kernel(float* __restrict__ ws, float* __restrict__ out, int mode) {
    if (mode == 0) {
        if (threadIdx.x == 0) out[BB*SS] = ws[0] / fmaxf(ws[1], 1.0f);
        return;
    }
    __shared__ float sl[4][2];
    const int tid = threadIdx.x, lane = tid & 63, wave = tid >> 6;
    const char* base = (const char*)ws + READS_BYTE;
    float L = 0.f, C = 0.f;
    for (int i = tid; i < 4096; i += 256) {
        const float* p = (const float*)(base + (size_t)i * PART_STRIDE_B);
        L += p[0]; C += p[1];
    }
    #pragma unroll
    for (int off = 32; off; off >>= 1) {
        L += __shfl_xor(L, off);
        C += __shfl_xor(C, off);
    }
    if (lane == 0) { sl[wave][0] = L; sl[wave][1] = C; }
    __syncthreads();
    if (tid == 0) {
        float LL = sl[0][0] + sl[1][0] + sl[2][0] + sl[3][0];
        float CC = sl[0][1] + sl[1][1] + sl[2][1] + sl[3][1];
        out[BB*SS] = LL / fmaxf(CC, 1.0f);
    }
}

// ======================= round-5 scan kernel (fallback, ws >= 26MB) =======================
__launch_bounds__(512, 2)
__global__ void scan_kernel(const int* __restrict__ q_data, const int* __restrict__ qa_data,
                            const float* __restrict__ target,
                            const float* __restrict__ init_mv,
                            const float* __restrict__ read_b,
                            const float* __restrict__ predict_w, const float* __restrict__ predict_b,
                            float* __restrict__ ws, float* __restrict__ out) {
    __shared__ __align__(128) char smem[50176];
    char*           cat16 = smem;
    float*          wf    = (float*)(smem + 12288);
    unsigned short* eaL   = (unsigned short*)(smem + 16640);
    unsigned short* rdp   = (unsigned short*)(smem + 33280);
    float*          rce_f = (float*)(smem + 41728);

    const int b    = blockIdx.x;
    const int tid  = threadIdx.x;
    const int lane = tid & 63;
    const int wave = tid >> 6;
    const int arow = lane & 15;
    const int ag   = lane >> 4;
    const int d    = tid & 255;
    const int half = tid >> 8;

    const unsigned short* wsb = (const unsigned short*)(ws + 16);
    const s8v* rtp = (const s8v*)(wsb + RTP_OFF);
    const float*          wtab = (const float*)((const char*)ws + WTAB_BYTE);
    const unsigned short* iet  = (const unsigned short*)((const char*)ws + IET_BYTE);
    const unsigned short* eat  = (const unsigned short*)((const char*)ws + EAT_BYTE);

    float mv[32];
    #pragma unroll
    for (int i = 0; i < 32; ++i) mv[i] = init_mv[(half*32 + i)*DV + d];

    const float rb    = read_b[wave*16 + arow];
    const float pw_lo = predict_w[lane];
    const float pw_hi = predict_w[lane + 64];

    const int base  = b * SS;
    const int erow  = tid >> 5;
    const int eunit = tid & 31;
    const int role  = tid >> 8;
    const int grow  = (tid >> 4) & 15;
    const int gunit = tid & 15;

    int iqa0, iq0, iqa1, iq1;
    u16x8 pe0, pe1, pie;
    float4 pwf;

    auto loadidx = [&](int cc, int& xa, int& xq) {
        xa = qa_data[base + cc*CHUNK + erow];
        xq = q_data [base + cc*CHUNK + grow];
    };
    auto loadrows = [&]() {
        const unsigned short* er_ptr = eat + (size_t)iqa0*512 + eunit*16;
        pe0 = *(const u16x8*)(er_ptr);
        pe1 = *(const u16x8*)(er_ptr + 8);
        if (role == 0) pwf = *(const float4*)(wtab + iq0*64 + gunit*4);
        else           pie = *(const u16x8*)(iet + (size_t)iq0*128 + gunit*8);
    };
    auto storerows = [&]() {
        *(u16x8*)(eaL + erow*520 + eunit*16)     = pe0;
        *(u16x8*)(eaL + erow*520 + eunit*16 + 8) = pe1;
        if (role == 0) *(float4*)((char*)wf + grow*272 + gunit*16) = pwf;
        else *(u16x8*)(cat16 + ((grow*768 + 512 + gunit*16) ^ ((grow & 7) << 4))) = pie;
    };

    loadidx(0, iqa0, iq0);
    loadrows();
    loadidx(1, iqa1, iq1);

    float local_loss = 0.0f, local_cnt = 0.0f;

    for (int c = 0; c < NCHUNK; ++c) {
        storerows();
        __syncthreads();
        iqa0 = iqa1; iq0 = iq1;
        if (c + 1 < NCHUNK) loadrows();
        { int c2 = (c + 2 < NCHUNK) ? c + 2 : NCHUNK - 1; loadidx(c2, iqa1, iq1); }

        for (int s = 0; s < CHUNK; ++s) {
            float e = bf2f(eaL[s*520 + d]);
            float a = bf2f(eaL[s*520 + 256 + d]);
            const float4* wr4 = (const float4*)(wf + s*68 + half*32);
            float r0 = 0.f, r1 = 0.f, r2 = 0.f, r3 = 0.f;
            #pragma unroll
            for (int j = 0; j < 8; ++j) {
                float4 w = wr4[j];
                r0 = fmaf(w.x, mv[j*4+0], r0); mv[j*4+0] = fmaf(w.x, fmaf(-mv[j*4+0], e, a), mv[j*4+0]);
                r1 = fmaf(w.y, mv[j*4+1], r1); mv[j*4+1] = fmaf(w.y, fmaf(-mv[j*4+1], e, a), mv[j*4+1]);
                r2 = fmaf(w.z, mv[j*4+2], r2); mv[j*4+2] = fmaf(w.z, fmaf(-mv[j*4+2], e, a), mv[j*4+2]);
                r3 = fmaf(w.w, mv[j*4+3], r3); mv[j*4+3] = fmaf(w.w, fmaf(-mv[j*4+3], e, a), mv[j*4+3]);
            }
            float rd = (r0 + r1) + (r2 + r3);
            if (half == 0) {
                *(unsigned short*)(cat16 + ((s*768 + d*2) ^ ((s & 7) << 4))) = f2bf(rd);
            } else {
                rdp[s*264 + d] = f2bf(rd);
            }
        }
        __syncthreads();

        if (half == 0) {
            #pragma unroll
            for (int s = 0; s < CHUNK; ++s) {
                unsigned short* p = (unsigned short*)(cat16 + ((s*768 + d*2) ^ ((s & 7) << 4)));
                *p = f2bf(bf2f(*p) + bf2f(rdp[s*264 + d]));
            }
        }
        __syncthreads();

        {
            f4v cc = {0.f,0.f,0.f,0.f};
            #pragma unroll
            for (int ks = 0; ks < 12; ++ks) {
                s8v a = *(const s8v*)(cat16 + ((arow*768 + ks*64 + ag*16) ^ ((arow & 7) << 4)));
                cc = MFMA16(a, rtp[(wave*12 + ks)*64 + lane], cc);
            }
            #pragma unroll
            for (int r = 0; r < 4; ++r)
                rce_f[(ag*4 + r)*132 + wave*16 + arow] = fast_tanh(cc[r] + rb);
        }
        __syncthreads();

        #pragma unroll
        for (int k = 0; k < 2; ++k) {
            int r = wave*2 + k;
            float p = fmaf(pw_lo, rce_f[r*132 + lane], pw_hi * rce_f[r*132 + 64 + lane]);
            #pragma unroll
            for (int off = 32; off; off >>= 1) p += __shfl_xor(p, off);
            if (lane == 0) {
                p += predict_b[0];
                int gi = b*SS + c*CHUNK + r;
                float t = target[gi];
                bool mask = t >= 0.0f;
                out[gi] = sigmoidf_(p);
                float pm = mask ? p : 0.0f;
                out[BB*SS + 1 + gi] = sigmoidf_(pm);
                out[2*BB*SS + 1 + gi] = mask ? t : 0.0f;
                if (mask) {
                    local_loss += fmaxf(p, 0.0f) - p*t + log1pf(__expf(-fabsf(p)));
                    local_cnt  += 1.0f;
                }
            }
        }
    }

    #pragma unroll
    for (int off = 32; off; off >>= 1) {
        local_loss += __shfl_xor(local_loss, off);
        local_cnt  += __shfl_xor(local_cnt, off);
    }
    if (lane == 0) {
        atomicAdd(&ws[0], local_loss);
        atomicAdd(&ws[1], local_cnt);
    }
}

extern "C" void kernel_launch(void* const* d_in, const int* in_sizes, int n_in,
                              void* d_out, int out_size, void* d_ws, size_t ws_size,
                              hipStream_t stream) {
    const int*   q_data    = (const int*)d_in[0];
    const int*   qa_data   = (const int*)d_in[1];
    const float* target    = (const float*)d_in[2];
    const float* q_embed   = (const float*)d_in[3];
    const float* qa_embed  = (const float*)d_in[4];
    const float* key_mem   = (const float*)d_in[5];
    const float* init_mv   = (const float*)d_in[6];
    const float* erase_w   = (const float*)d_in[7];
    const float* erase_b   = (const float*)d_in[8];
    const float* add_w     = (const float*)d_in[9];
    const float* add_b     = (const float*)d_in[10];
    const float* input_w   = (const float*)d_in[11];
    const float* input_b   = (const float*)d_in[12];
    const float* read_w    = (const float*)d_in[13];
    const float* read_b    = (const float*)d_in[14];
    const float* predict_w = (const float*)d_in[15];
    const float* predict_b = (const float*)d_in[16];

    float* ws  = (float*)d_ws;
    float* out = (float*)d_out;

    hipLaunchKernelGGL(prep_kernel, dim3(256), dim3(256), 0, stream,
                       erase_w, add_w, key_mem, input_w, read_w, ws);
    if (ws_size >= WS_NEED3) {
        hipLaunchKernelGGL(table_kernel, dim3(470), dim3(256), 0, stream,
                           q_embed, qa_embed, erase_b, add_b, input_b, read_b, 1, ws);
        hipLaunchKernelGGL(scan2_kernel, dim3(2048), dim3(256), 0, stream,
                           q_data, qa_data, init_mv, ws);
        hipLaunchKernelGGL(rce_kernel, dim3(4096), dim3(256), 0, stream,
                           q_data, target, predict_w, predict_b, ws, out);
        hipLaunchKernelGGL(finish_kernel, dim3(1), dim3(256), 0, stream, ws, out, 1);
    } else {
        hipLaunchKernelGGL(table_kernel, dim3(470), dim3(256), 0, stream,
                           q_embed, qa_embed, erase_b, add_b, input_b, read_b, 0, ws);
        hipLaunchKernelGGL(scan_kernel, dim3(BB), dim3(512), 0, stream,
                           q_data, qa_data, target, init_mv,
                           read_b, predict_w, predict_b, ws, out);
        hipLaunchKernelGGL(finish_kernel, dim3(1), dim3(256), 0, stream, ws, out, 0);
    }
}